// Round 5
// baseline (458.887 us; speedup 1.0000x reference)
//
#include <hip/hip_runtime.h>
#include <cstdint>
#include <cstddef>

#define NH   16
#define HD   64
#define RLEN 2048
#define BSZ  2
#define SLEN 64
#define NZ   64
#define ED   1024
#define KTOT 2112   // SLEN + RLEN
#define LDK  72     // padded LDS row stride for Ps only
#define NSPLIT 8    // sum_attn key splits

typedef __bf16 bf16_t;
typedef bf16_t bf16x8 __attribute__((ext_vector_type(8)));
typedef bf16_t bf16x4 __attribute__((ext_vector_type(4)));
typedef float  f32x4  __attribute__((ext_vector_type(4)));

__device__ __forceinline__ f32x4 mfma16(bf16x8 a, bf16x8 b, f32x4 c) {
    return __builtin_amdgcn_mfma_f32_16x16x32_bf16(a, b, c, 0, 0, 0);
}

// async global->LDS DMA, 16B per lane; LDS dest = base + lane*16
__device__ __forceinline__ void dma16(const void* g, void* l) {
    __builtin_amdgcn_global_load_lds(
        (const __attribute__((address_space(1))) unsigned int*)g,
        (__attribute__((address_space(3))) unsigned int*)l, 16, 0, 0);
}

// Frag-major K layout per bh (2048 keys x 64 d):
//   granule(key,d8): tile=key>>6, nt=(key>>4)&3, l15=key&15, kblk=d8>>2, quad=d8&3
//   elem off = (((tile*4+nt)*2+kblk)*64 + quad*16 + l15)*8 + (d&7)
// Frag-major V^T layout: granule(dcol,key8): nt=d>>4, l15=d&15, kblk=key8>>2, quad=key8&3.

// ------------------------------------------------------------------
// m97-style GEMM: A bf16 [M][K], Bt bf16 [N][K]; BK=64, tile BM x 128,
// global_load_lds staging with XOR-swizzled granules.
// mode 1 (QKV): n in [0,3072): seg0->qb bf16 head *0.125, seg1->k f32, seg2->v f32
// mode 0: o1 fp32 [M][N] = acc + b0[n]
// ------------------------------------------------------------------
template<int BM>
__global__ __launch_bounds__(256) void gemm_fast(
    const bf16_t* __restrict__ A, const bf16_t* __restrict__ Bt,
    const float* __restrict__ b0, const float* __restrict__ b1,
    const float* __restrict__ b2,
    bf16_t* __restrict__ oq, float* __restrict__ o1, float* __restrict__ o2,
    int M, int K, int N, int mode)
{
    constexpr int MT = BM / 64;     // 16-row frags per wave
    __shared__ __align__(16) bf16_t As[BM * 64];
    __shared__ __align__(16) bf16_t Bs[128 * 64];

    const int t = threadIdx.x;
    const int wave = t >> 6, lane = t & 63;
    const int quad = lane >> 4, l15 = lane & 15;
    const int rsub = lane >> 3, gq = lane & 7;
    const int m0 = blockIdx.y * BM, n0 = blockIdx.x * 128;

    f32x4 acc[MT][8];
#pragma unroll
    for (int i = 0; i < MT; i++)
#pragma unroll
        for (int j = 0; j < 8; j++) acc[i][j] = (f32x4){0.f, 0.f, 0.f, 0.f};

    for (int k0 = 0; k0 < K; k0 += 64) {
        // stage A (BM x 64) : each wave loads its own strip, 8 rows per DMA
#pragma unroll
        for (int j = 0; j < BM / 32; j++) {
            int row = wave * (BM / 4) + j * 8 + rsub;
            const bf16_t* g = A + (size_t)(m0 + row) * K + k0 + ((gq ^ (row & 7)) * 8);
            dma16(g, As + (wave * (BM / 4) + j * 8) * 64);
        }
        // stage B (128 x 64)
#pragma unroll
        for (int j = 0; j < 4; j++) {
            int row = wave * 32 + j * 8 + rsub;
            const bf16_t* g = Bt + (size_t)(n0 + row) * K + k0 + ((gq ^ (row & 7)) * 8);
            dma16(g, Bs + (wave * 32 + j * 8) * 64);
        }
        __syncthreads();

#pragma unroll
        for (int kk = 0; kk < 2; kk++) {
            const int pg = ((kk * 4 + quad) ^ (l15 & 7)) * 8;
            bf16x8 af[MT], bf[8];
#pragma unroll
            for (int mt = 0; mt < MT; mt++)
                af[mt] = *(const bf16x8*)(As + (wave * (BM / 4) + mt * 16 + l15) * 64 + pg);
#pragma unroll
            for (int nt = 0; nt < 8; nt++)
                bf[nt] = *(const bf16x8*)(Bs + (nt * 16 + l15) * 64 + pg);
#pragma unroll
            for (int mt = 0; mt < MT; mt++)
#pragma unroll
                for (int nt = 0; nt < 8; nt++)
                    acc[mt][nt] = mfma16(af[mt], bf[nt], acc[mt][nt]);
        }
        __syncthreads();
    }

#pragma unroll
    for (int mt = 0; mt < MT; mt++)
#pragma unroll
        for (int nt = 0; nt < 8; nt++)
#pragma unroll
            for (int reg = 0; reg < 4; reg++) {
                int m = m0 + wave * (BM / 4) + mt * 16 + quad * 4 + reg;
                int n = n0 + nt * 16 + l15;
                if (mode == 0) {
                    o1[(size_t)m * N + n] = acc[mt][nt][reg] + b0[n];
                } else {
                    int seg = n >> 10, nl = n & 1023;
                    const float* bias = (seg == 0) ? b0 : (seg == 1) ? b1 : b2;
                    float c = acc[mt][nt][reg] + bias[nl];
                    int h = nl >> 6, d = nl & 63;
                    int r = m >> 1, bb = m & 1;
                    size_t off = (((size_t)bb * NH + h) * RLEN + r) * HD + d;
                    if (seg == 0)      oq[off] = (bf16_t)(c * 0.125f);
                    else if (seg == 1) o1[off] = c;
                    else               o2[off] = c;
                }
            }
}

// ------------------------------------------------------------------
// 64x128 MFMA GEMM (small r0 gemm only), padded LDS.
// ------------------------------------------------------------------
__global__ __launch_bounds__(256) void gemm_mfma(
    const bf16_t* __restrict__ A, const bf16_t* __restrict__ Bt,
    const float* __restrict__ bias, float* __restrict__ outf,
    int M, int K, int N, int Rr)
{
    constexpr int LDA = 40;
    __shared__ __align__(16) bf16_t As[64 * LDA];
    __shared__ __align__(16) bf16_t Bs[128 * LDA];

    const int t = threadIdx.x;
    const int wave = t >> 6, lane = t & 63;
    const int quad = lane >> 4, l15 = lane & 15;
    const int wrow = wave >> 1, wcol = wave & 1;
    const int m0 = blockIdx.y * 64, n0 = blockIdx.x * 128;

    f32x4 acc[2][4];
#pragma unroll
    for (int i = 0; i < 2; i++)
#pragma unroll
        for (int j = 0; j < 4; j++) acc[i][j] = (f32x4){0.f, 0.f, 0.f, 0.f};

    const int srow = t >> 2, sseg = (t & 3) * 8;

    for (int k0 = 0; k0 < K; k0 += 32) {
        bf16x8 av  = *(const bf16x8*)(A  + (size_t)(m0 + srow) * K + k0 + sseg);
        bf16x8 bv0 = *(const bf16x8*)(Bt + (size_t)(n0 + srow) * K + k0 + sseg);
        bf16x8 bv1 = *(const bf16x8*)(Bt + (size_t)(n0 + 64 + srow) * K + k0 + sseg);
        __syncthreads();
        *(bf16x8*)(As + srow * LDA + sseg)        = av;
        *(bf16x8*)(Bs + srow * LDA + sseg)        = bv0;
        *(bf16x8*)(Bs + (64 + srow) * LDA + sseg) = bv1;
        __syncthreads();

        bf16x8 af[2], bf[4];
#pragma unroll
        for (int mt = 0; mt < 2; mt++)
            af[mt] = *(const bf16x8*)(As + (wrow * 32 + mt * 16 + l15) * LDA + quad * 8);
#pragma unroll
        for (int nt = 0; nt < 4; nt++)
            bf[nt] = *(const bf16x8*)(Bs + (wcol * 64 + nt * 16 + l15) * LDA + quad * 8);
#pragma unroll
        for (int mt = 0; mt < 2; mt++)
#pragma unroll
            for (int nt = 0; nt < 4; nt++)
                acc[mt][nt] = mfma16(af[mt], bf[nt], acc[mt][nt]);
    }

#pragma unroll
    for (int mt = 0; mt < 2; mt++)
#pragma unroll
        for (int nt = 0; nt < 4; nt++)
#pragma unroll
            for (int reg = 0; reg < 4; reg++) {
                int m = m0 + wrow * 32 + mt * 16 + quad * 4 + reg;
                int n = n0 + wcol * 64 + nt * 16 + l15;
                if (m >= M) continue;
                float c = acc[mt][nt][reg] + bias[n];
                int h = n >> 6, d = n & 63;
                outf[(((size_t)h) * Rr + m) * HD + d] = c;   // [h][z][d], Rr=NZ
            }
}

// ------------------------------------------------------------------
// K LayerNorm -> frag-major bf16. One wave per key row.
// ------------------------------------------------------------------
__global__ __launch_bounds__(256) void ln_k_frag(
    const float* __restrict__ x, const float* __restrict__ g, const float* __restrict__ b,
    bf16_t* __restrict__ kfm)
{
    int row  = blockIdx.x * 4 + (threadIdx.x >> 6);
    int lane = threadIdx.x & 63;
    float v = x[(size_t)row * HD + lane];
    float s1 = v, s2 = v * v;
#pragma unroll
    for (int o = 32; o > 0; o >>= 1) {
        s1 += __shfl_xor(s1, o);
        s2 += __shfl_xor(s2, o);
    }
    float mean = s1 * (1.f / 64.f);
    float var  = s2 * (1.f / 64.f) - mean * mean;
    float y = (v - mean) * rsqrtf(var + 1e-5f) * g[lane] + b[lane];
    int bh = row >> 11, r = row & 2047, d = lane;
    size_t off = (size_t)bh * 131072 +
        (size_t)(((((r >> 6) * 4 + ((r >> 4) & 3)) * 2 + (d >> 5)) * 64
                  + ((d >> 3) & 3) * 16 + (r & 15)) * 8 + (d & 7));
    kfm[off] = (bf16_t)y;
}

// ------------------------------------------------------------------
// V LayerNorm + transpose -> frag-major bf16 V^T.
// grid (RLEN/64, BSZ*NH).
// ------------------------------------------------------------------
__global__ __launch_bounds__(256) void lnv_frag(
    const float* __restrict__ v, const float* __restrict__ g,
    const float* __restrict__ b, bf16_t* __restrict__ vfm)
{
    __shared__ float tile[64][65];
    const int bh = blockIdx.y, tidx = blockIdx.x;
    const int t = threadIdx.x;
    const int wave = t >> 6, lane = t & 63;

#pragma unroll
    for (int i = 0; i < 16; i++) {
        int rl = wave * 16 + i;
        float x = v[((size_t)bh * RLEN + tidx * 64 + rl) * HD + lane];
        float s1 = x, s2 = x * x;
#pragma unroll
        for (int o = 32; o > 0; o >>= 1) {
            s1 += __shfl_xor(s1, o);
            s2 += __shfl_xor(s2, o);
        }
        float mean = s1 * (1.f / 64.f);
        float var  = s2 * (1.f / 64.f) - mean * mean;
        tile[rl][lane] = (x - mean) * rsqrtf(var + 1e-5f) * g[lane] + b[lane];
    }
    __syncthreads();
    int d = t >> 2, rs = (t & 3) * 16;
    bf16x8 o0, o1;
#pragma unroll
    for (int j = 0; j < 8; j++) {
        o0[j] = (bf16_t)tile[rs + j][d];
        o1[j] = (bf16_t)tile[rs + 8 + j][d];
    }
    size_t base = (size_t)bh * 131072;
    size_t off0 = base + (size_t)((((tidx * 4 + (d >> 4)) * 2 + (rs >> 5)) * 64
                  + ((rs >> 3) & 3) * 16 + (d & 15)) * 8);
    int rs2 = rs + 8;
    size_t off1 = base + (size_t)((((tidx * 4 + (d >> 4)) * 2 + (rs2 >> 5)) * 64
                  + ((rs2 >> 3) & 3) * 16 + (d & 15)) * 8);
    *(bf16x8*)(vfm + off0) = o0;
    *(bf16x8*)(vfm + off1) = o1;
}

// ------------------------------------------------------------------
__global__ __launch_bounds__(256) void cvt_bf16(
    const float* __restrict__ src, bf16_t* __restrict__ dst, int n)
{
    int i = (blockIdx.x * 256 + threadIdx.x) * 4;
    if (i < n) {
        float4 v = *(const float4*)(src + i);
        bf16x4 o;
        o[0] = (bf16_t)v.x; o[1] = (bf16_t)v.y; o[2] = (bf16_t)v.z; o[3] = (bf16_t)v.w;
        *(bf16x4*)(dst + i) = o;
    }
}

// ------------------------------------------------------------------
// Batched weight transpose+cvt -> [n][k] bf16.
// ------------------------------------------------------------------
__global__ __launch_bounds__(256) void wt_batch(
    const float* __restrict__ Wq, const float* __restrict__ Wk,
    const float* __restrict__ Wv, const float* __restrict__ Wo,
    const float* __restrict__ Wr0,
    bf16_t* __restrict__ wqt, bf16_t* __restrict__ wkt,
    bf16_t* __restrict__ wvt, bf16_t* __restrict__ wot,
    bf16_t* __restrict__ wr0t)
{
    __shared__ float tile[64][65];
    const int bid = blockIdx.x;
    const float* src; bf16_t* dst; int R, C, r0, c0;
    if (bid < 1024) {
        int sel = bid >> 8, local = bid & 255;
        src = (sel == 0) ? Wq : (sel == 1) ? Wk : (sel == 2) ? Wv : Wo;
        dst = (sel == 0) ? wqt : (sel == 1) ? wkt : (sel == 2) ? wvt : wot;
        R = ED; C = ED; r0 = (local >> 4) * 64; c0 = (local & 15) * 64;
    } else {
        src = Wr0; dst = wr0t; R = NZ; C = ED; r0 = 0; c0 = (bid - 1024) * 64;
    }
    const int t = threadIdx.x;
#pragma unroll
    for (int i = 0; i < 4; i++) {
        int idx = t + i * 256;
        int r = idx >> 4, c = (idx & 15) * 4;
        float4 vv = *(const float4*)(src + (size_t)(r0 + r) * C + c0 + c);
        tile[r][c] = vv.x; tile[r][c + 1] = vv.y; tile[r][c + 2] = vv.z; tile[r][c + 3] = vv.w;
    }
    __syncthreads();
    int cc = t >> 2, rs = (t & 3) * 16;
    bf16x8 o0, o1;
#pragma unroll
    for (int j = 0; j < 8; j++) {
        o0[j] = (bf16_t)tile[rs + j][cc];
        o1[j] = (bf16_t)tile[rs + 8 + j][cc];
    }
    *(bf16x8*)(dst + (size_t)(c0 + cc) * R + r0 + rs) = o0;
    *(bf16x8*)(dst + (size_t)(c0 + cc) * R + r0 + rs + 8) = o1;
}

// ------------------------------------------------------------------
__global__ __launch_bounds__(256) void sumq_gather(
    const float* __restrict__ emb, const int* __restrict__ ids,
    bf16_t* __restrict__ sum_q)
{
    int sb = blockIdx.x;
    int s = sb >> 1, b = sb & 1;
    int id = ids[b * SLEN + s];
    const float* src = emb + (size_t)id * ED;
    for (int e = threadIdx.x; e < ED; e += 256) {
        int h = e >> 6, d = e & 63;
        sum_q[(((size_t)b * NH + h) * SLEN + s) * HD + d] = (bf16_t)(src[e] * 0.125f);
    }
}

// stage one 64-key frag-major tile (K + V^T, 8KB each) via DMA.
// wave w loads sub-blocks (nt=w, kblk=0/1) of each.
__device__ __forceinline__ void stage_kv(
    const bf16_t* __restrict__ kt, const bf16_t* __restrict__ vt,
    bf16_t* KB, bf16_t* VB, int wave, int lane)
{
    const int o0 = (wave * 2 + 0) * 512;
    const int o1 = (wave * 2 + 1) * 512;
    dma16(kt + o0 + lane * 8, KB + o0);
    dma16(kt + o1 + lane * 8, KB + o1);
    dma16(vt + o0 + lane * 8, VB + o0);
    dma16(vt + o1 + lane * 8, VB + o1);
}

// ------------------------------------------------------------------
// Summary attention, split-K MFMA flash w/ DMA staging. grid (32, NSPLIT).
// ------------------------------------------------------------------
__global__ __launch_bounds__(256) void sum_attn_split(
    const bf16_t* __restrict__ Qb,   // sum_q [bh][s][d] row-major
    const bf16_t* __restrict__ kfm, const bf16_t* __restrict__ vfm,
    const float*  __restrict__ r0,
    const int*    __restrict__ rel_idx,
    float* __restrict__ po, float* __restrict__ pm, float* __restrict__ pl)
{
    const int bh = blockIdx.x;
    const int split = blockIdx.y;
    const int b = bh >> 4, h = bh & 15;
    const int t = threadIdx.x;
    const int wave = t >> 6, lane = t & 63;
    const int quad = lane >> 4, l15 = lane & 15;

    __shared__ __align__(16) bf16_t Kbuf[2][4096];
    __shared__ __align__(16) bf16_t Vbuf[2][4096];
    __shared__ __align__(16) bf16_t Ps[64 * LDK];
    __shared__ __align__(16) bf16_t qrs[64 * 64];

    const bf16_t* Qrow = Qb + ((size_t)bh * SLEN + wave * 16 + l15) * HD;
    bf16x8 qf0 = *(const bf16x8*)(Qrow + quad * 8);
    bf16x8 qf1 = *(const bf16x8*)(Qrow + 32 + quad * 8);

    const bf16_t* ktile0 = kfm + (size_t)bh * 131072 + (size_t)(split * 4) * 4096;
    const bf16_t* vtile0 = vfm + (size_t)bh * 131072 + (size_t)(split * 4) * 4096;
    stage_kv(ktile0, vtile0, Kbuf[0], Vbuf[0], wave, lane);

#pragma unroll
    for (int nt = 0; nt < 4; nt++) {
        f32x4 qa = {0.f, 0.f, 0.f, 0.f};
        const float* rp = r0 + ((size_t)h * NZ + l15 + 16 * nt) * HD + quad * 8;
        float4 a0 = *(const float4*)(rp);
        float4 a1 = *(const float4*)(rp + 4);
        bf16x8 bf;
        bf[0] = (bf16_t)a0.x; bf[1] = (bf16_t)a0.y; bf[2] = (bf16_t)a0.z; bf[3] = (bf16_t)a0.w;
        bf[4] = (bf16_t)a1.x; bf[5] = (bf16_t)a1.y; bf[6] = (bf16_t)a1.z; bf[7] = (bf16_t)a1.w;
        qa = mfma16(qf0, bf, qa);
        float4 b0 = *(const float4*)(rp + 32);
        float4 b1 = *(const float4*)(rp + 36);
        bf[0] = (bf16_t)b0.x; bf[1] = (bf16_t)b0.y; bf[2] = (bf16_t)b0.z; bf[3] = (bf16_t)b0.w;
        bf[4] = (bf16_t)b1.x; bf[5] = (bf16_t)b1.y; bf[6] = (bf16_t)b1.z; bf[7] = (bf16_t)b1.w;
        qa = mfma16(qf1, bf, qa);
#pragma unroll
        for (int reg = 0; reg < 4; reg++)
            qrs[(wave * 16 + quad * 4 + reg) * 64 + l15 + 16 * nt] = (bf16_t)qa[reg];
    }

    f32x4 O[4];
    float m_i[4], l_i[4];
#pragma unroll
    for (int nt = 0; nt < 4; nt++) O[nt] = (f32x4){0.f, 0.f, 0.f, 0.f};
#pragma unroll
    for (int r = 0; r < 4; r++) { m_i[r] = -1e30f; l_i[r] = 0.f; }

    for (int i = 0; i < 4; i++) {
        const bf16_t* KB = Kbuf[i & 1];
        const bf16_t* VB = Vbuf[i & 1];
        __syncthreads();
        if (i < 3)
            stage_kv(ktile0 + (size_t)(i + 1) * 4096, vtile0 + (size_t)(i + 1) * 4096,
                     Kbuf[(i + 1) & 1], Vbuf[(i + 1) & 1], wave, lane);

        const int kk0 = (split * 4 + i) * 64;
        f32x4 S[4];
#pragma unroll
        for (int nt = 0; nt < 4; nt++) {
            f32x4 acc = {0.f, 0.f, 0.f, 0.f};
            bf16x8 kf0 = *(const bf16x8*)(KB + ((nt * 2 + 0) * 64 + lane) * 8);
            bf16x8 kf1 = *(const bf16x8*)(KB + ((nt * 2 + 1) * 64 + lane) * 8);
            acc = mfma16(qf0, kf0, acc);
            acc = mfma16(qf1, kf1, acc);
            S[nt] = acc;
        }

        const int* rrow = rel_idx + ((size_t)b * KTOT + wave * 16 + quad * 4) * RLEN + kk0 + l15;
#pragma unroll
        for (int reg = 0; reg < 4; reg++) {
            const int* rp = rrow + (size_t)reg * RLEN;
            int qlocal = wave * 16 + quad * 4 + reg;
#pragma unroll
            for (int nt = 0; nt < 4; nt++) {
                int idx = rp[16 * nt];
                S[nt][reg] += (float)qrs[qlocal * 64 + idx];
            }
        }

        float tmax[4];
#pragma unroll
        for (int reg = 0; reg < 4; reg++) {
            float v = fmaxf(fmaxf(S[0][reg], S[1][reg]), fmaxf(S[2][reg], S[3][reg]));
#pragma unroll
            for (int o = 8; o > 0; o >>= 1) v = fmaxf(v, __shfl_xor(v, o));
            tmax[reg] = v;
        }
        float alpha[4], psum[4];
#pragma unroll
        for (int reg = 0; reg < 4; reg++) {
            float mn = fmaxf(m_i[reg], tmax[reg]);
            alpha[reg] = __expf(m_i[reg] - mn);
            m_i[reg] = mn;
            psum[reg] = 0.f;
        }
#pragma unroll
        for (int nt = 0; nt < 4; nt++)
#pragma unroll
            for (int reg = 0; reg < 4; reg++) {
                float p = __expf(S[nt][reg] - m_i[reg]);
                S[nt][reg] = p;
                psum[reg] += p;
            }
#pragma unroll
        for (int reg = 0; reg < 4; reg++) {
#pragma unroll
            for (int o = 8; o > 0; o >>= 1) psum[reg] += __shfl_xor(psum[reg], o);
            l_i[reg] = l_i[reg] * alpha[reg] + psum[reg];
        }
#pragma unroll
        for (int nt = 0; nt < 4; nt++) {
            O[nt][0] *= alpha[0]; O[nt][1] *= alpha[1];
            O[nt][2] *= alpha[2]; O[nt][3] *= alpha[3];
        }

#pragma unroll
        for (int nt = 0; nt < 4; nt++)
#pragma unroll
            for (int reg = 0; reg < 4; reg++)
                Ps[(wave * 16 + quad * 4 + reg) * LDK + l15 + 16 * nt] = (bf16_t)S[nt][reg];

        bf16x8 pf0 = *(const bf16x8*)(Ps + (wave * 16 + l15) * LDK + quad * 8);
        bf16x8 pf1 = *(const bf16x8*)(Ps + (wave * 16 + l15) * LDK + 32 + quad * 8);
#pragma unroll
        for (int nt = 0; nt < 4; nt++) {
            bf16x8 vf0 = *(const bf16x8*)(VB + ((nt * 2 + 0) * 64 + lane) * 8);
            bf16x8 vf1 = *(const bf16x8*)(VB + ((nt * 2 + 1) * 64 + lane) * 8);
            O[nt] = mfma16(pf0, vf0, O[nt]);
            O[nt] = mfma16(pf1, vf1, O[nt]);
        }
    }

    const size_t pslot = (size_t)bh * NSPLIT + split;
#pragma unroll
    for (int nt = 0; nt < 4; nt++)
#pragma unroll
        for (int reg = 0; reg < 4; reg++) {
            int sq = wave * 16 + quad * 4 + reg;
            po[(pslot * SLEN + sq) * HD + l15 + 16 * nt] = O[nt][reg];
        }
#pragma unroll
    for (int reg = 0; reg < 4; reg++) {
        int sq = wave * 16 + quad * 4 + reg;
        if (l15 == 0) {
            pm[pslot * SLEN + sq] = m_i[reg];
            pl[pslot * SLEN + sq] = l_i[reg];
        }
    }
}

// ------------------------------------------------------------------
__global__ __launch_bounds__(256) void sum_reduce(
    const float* __restrict__ po, const float* __restrict__ pm,
    const float* __restrict__ pl, float* __restrict__ sum_x2)
{
    const int bh = blockIdx.x;
    const int sg0 = blockIdx.y * 16;
    const int t = threadIdx.x;
    const int d = t & 63, si = t >> 6;
#pragma unroll
    for (int i = 0; i < 4; i++) {
        int s = sg0 + si * 4 + i;
        float M = -1e30f, mm[NSPLIT];
#pragma unroll
        for (int j = 0; j < NSPLIT; j++) {
            mm[j] = pm[((size_t)bh * NSPLIT + j) * SLEN + s];
            M = fmaxf(M, mm[j]);
        }
        float L = 0.f, acc = 0.f;
#pragma unroll
        for (int j = 0; j < NSPLIT; j++) {
            float a = __expf(mm[j] - M);
            L += pl[((size_t)bh * NSPLIT + j) * SLEN + s] * a;
            acc += po[(((size_t)bh * NSPLIT + j) * SLEN + s) * HD + d] * a;
        }
        sum_x2[((size_t)bh * SLEN + s) * HD + d] = acc / L;
    }
}

// ------------------------------------------------------------------
// sum_k2 / sum_v2: y = LN(x @ W + b); write frag-major bf16 single tile.
// ------------------------------------------------------------------
__global__ __launch_bounds__(64) void k2v2(
    const float* __restrict__ sum_x2,
    const float* __restrict__ Wk2, const float* __restrict__ bk2,
    const float* __restrict__ Wv2, const float* __restrict__ bv2,
    const float* __restrict__ gk, const float* __restrict__ bk,
    const float* __restrict__ gv, const float* __restrict__ bv,
    bf16_t* __restrict__ k2fm, bf16_t* __restrict__ v2fm)
{
    int row = blockIdx.x;              // bh*64 + s
    int d = threadIdx.x;
    int bh = row >> 6, s = row & 63;
    __shared__ float xs[64];
    xs[d] = sum_x2[(size_t)row * HD + d];
    __syncthreads();

#pragma unroll
    for (int which = 0; which < 2; which++) {
        const float* W  = which ? Wv2 : Wk2;
        const float* bi = which ? bv2 : bk2;
        const float* g  = which ? gv : gk;
        const float* bb = which ? bv : bk;
        float a = bi[d];
#pragma unroll
        for (int j = 0; j < 64; j++) a += xs[j] * W[j * HD + d];
        float s1 = a, s2 = a * a;
#pragma unroll
        for (int o = 32; o > 0; o >>= 1) {
            s1 += __shfl_xor(s1, o);
            s2 += __shfl_xor(s2, o);
        }
        float mean = s1 * (1.f / 64.f);
        float var  = s2 * (1.f / 64.f) - mean * mean;
        float y = (a - mean) * rsqrtf(var + 1e-5f) * g[d] + bb[d];
        if (which == 0) {
            // K frag: key=s, col=d
            size_t off = (size_t)bh * 4096 +
                (size_t)(((((s >> 4) & 3) * 2 + (d >> 5)) * 64
                          + ((d >> 3) & 3) * 16 + (s & 15)) * 8 + (d & 7));
            k2fm[off] = (bf16_t)y;
        } else {
            // V^T frag: dcol=d, key=s
            size_t off = (size_t)bh * 4096 +
                (size_t)((((d >> 4) * 2 + (s >> 5)) * 64
                          + ((s >> 3) & 3) * 16 + (d & 15)) * 8 + (s & 7));
            v2fm[off] = (bf16_t)y;
        }
    }
}

// ------------------------------------------------------------------
// Main attention, MFMA flash: frag-major K/V via DMA, double-buffered.
// Block = (b,h, 64-q tile), 4 waves x 16 q-rows. 33 tiles.
// ------------------------------------------------------------------
__global__ __launch_bounds__(256) void reg_attn_mfma(
    const bf16_t* __restrict__ Qb,    // [bh][r][d] row-major
    const bf16_t* __restrict__ kfm, const bf16_t* __restrict__ vfm,
    const bf16_t* __restrict__ k2fm, const bf16_t* __restrict__ v2fm,
    const float*  __restrict__ r0,
    const int*    __restrict__ rel_idx,
    bf16_t* __restrict__ attn_out)    // [r][b][E] bf16
{
    const int bid = blockIdx.x;
    const int bh = (bid & 7) * 4 + ((bid >> 3) & 3);
    const int qt = bid >> 5;
    const int b = bh >> 4, h = bh & 15;
    const int q0 = qt * 64;

    const int t = threadIdx.x;
    const int wave = t >> 6, lane = t & 63;
    const int quad = lane >> 4, l15 = lane & 15;

    __shared__ __align__(16) bf16_t Kbuf[2][4096];
    __shared__ __align__(16) bf16_t Vbuf[2][4096];
    __shared__ __align__(16) bf16_t Ps[64 * LDK];
    __shared__ __align__(16) bf16_t qrs[64 * 64];

    const bf16_t* Qrow = Qb + (((size_t)bh * RLEN) + q0 + wave * 16 + l15) * HD;
    bf16x8 qf0 = *(const bf16x8*)(Qrow + quad * 8);
    bf16x8 qf1 = *(const bf16x8*)(Qrow + 32 + quad * 8);

    const bf16_t* kbase = kfm + (size_t)bh * 131072;
    const bf16_t* vbase = vfm + (size_t)bh * 131072;
    // tile 0 = summary keys
    stage_kv(k2fm + (size_t)bh * 4096, v2fm + (size_t)bh * 4096,
             Kbuf[0], Vbuf[0], wave, lane);

#pragma unroll
    for (int nt = 0; nt < 4; nt++) {
        f32x4 qa = {0.f, 0.f, 0.f, 0.f};
        const float* rp = r0 + ((size_t)h * NZ + l15 + 16 * nt) * HD + quad * 8;
        float4 a0 = *(const float4*)(rp);
        float4 a1 = *(const float4*)(rp + 4);
        bf16x8 bf;
        bf[0] = (bf16_t)a0.x; bf[1] = (bf16_t)a0.y; bf[2] = (bf16_t)a0.z; bf[3] = (bf16_t)a0.w;
        bf[4] = (bf16_t)a1.x; bf[5] = (bf16_t)a1.y; bf[6] = (bf16_t)a1.z; bf[7] = (bf16_t)a1.w;
        qa = mfma16(qf0, bf, qa);
        float4 b0 = *(const float4*)(rp + 32);
        float4 b1 = *(const float4*)(rp + 36);
        bf[0] = (bf16_t)b0.x; bf[1] = (bf16_t)b0.y; bf[2] = (bf16_t)b0.z; bf[3] = (bf16_t)b0.w;
        bf[4] = (bf16_t)b1.x; bf[5] = (bf16_t)b1.y; bf[6] = (bf16_t)b1.z; bf[7] = (bf16_t)b1.w;
        qa = mfma16(qf1, bf, qa);
#pragma unroll
        for (int reg = 0; reg < 4; reg++)
            qrs[(wave * 16 + quad * 4 + reg) * 64 + l15 + 16 * nt] = (bf16_t)qa[reg];
    }

    f32x4 O[4];
    float m_i[4], l_i[4];
#pragma unroll
    for (int nt = 0; nt < 4; nt++) O[nt] = (f32x4){0.f, 0.f, 0.f, 0.f};
#pragma unroll
    for (int r = 0; r < 4; r++) { m_i[r] = -1e30f; l_i[r] = 0.f; }

    const int* relbase = rel_idx + ((size_t)b * KTOT + SLEN + q0 + wave * 16 + quad * 4) * RLEN + l15;
    int crel[4][4];

    for (int tile = 0; tile < 33; tile++) {
        const bf16_t* KB = Kbuf[tile & 1];
        const bf16_t* VB = Vbuf[tile & 1];
        __syncthreads();
        if (tile < 32)
            stage_kv(kbase + (size_t)tile * 4096, vbase + (size_t)tile * 4096,
                     Kbuf[(tile + 1) & 1], Vbuf[(tile + 1) & 1], wave, lane);

        // prefetch next tile's rel ints
        int nrel[4][4];
        if (tile < 32) {
            const int* rr = relbase + tile * 64;
#pragma unroll
            for (int reg = 0; reg < 4; reg++)
#pragma unroll
                for (int nt = 0; nt < 4; nt++)
                    nrel[reg][nt] = rr[(size_t)reg * RLEN + 16 * nt];
        }

        f32x4 S[4];
#pragma unroll
        for (int nt = 0; nt < 4; nt++) {
            f32x4 acc = {0.f, 0.f, 0.f, 0.f};
            bf16x8 kf0 = *(const bf16x8*)(KB + ((nt * 2 + 0) * 64 + lane) * 8);
            bf16x8 kf1 = *(const bf16x8*)(KB + ((nt * 2 + 1) * 64 + lane) * 8);
            acc = mfma16(qf0, kf0, acc);
            acc = mfma16(qf1, kf1, acc);
            S[nt] = acc;
        }

        if (tile > 0) {
#pragma unroll
            for (int reg = 0; reg < 4; reg++) {
                int qlocal = wave * 16 + quad * 4 + reg;
#pragma unroll
                for (int nt = 0; nt < 4; nt++)
                    S[nt][reg] += (float)qrs[qlocal * 64 + crel[reg][nt]];
            }
        }

        float tmax[4];
#pragma unroll
        for (int reg = 0; reg < 4; reg++) {
            float v = fmaxf(fmaxf(S[0][reg], S[1][reg]), fmaxf(S[2][reg], S[3][reg]));
#pragma unroll
            for (int o = 8; o > 0; o >>= 1) v = fmaxf(v, __shfl_xor(v, o));
            tmax[reg] = v;
        }
        float alpha[4], psum[4];
#pragma unroll
        for (int reg = 0; reg < 4; reg++) {
            float mn = fmaxf(m_i[reg], tmax[reg]);
            alpha[reg] = __expf(m_i[reg] - mn);
            m_i[reg] = mn;
            psum[reg] = 0.f;
        }
#pragma unroll
        for (int nt = 0; nt < 4; nt++)
#pragma unroll
            for (int reg = 0; reg < 4; reg++) {
                float p = __expf(S[nt][reg] - m_i[reg]);
                S[nt][reg] = p;
                psum[reg] += p;
            }
#pragma unroll
        for (int reg = 0; reg < 4; reg++) {
#pragma unroll
            for (int o = 8; o > 0; o >>= 1) psum[reg] += __shfl_xor(psum[reg], o);
            l_i[reg] = l_i[reg] * alpha[reg] + psum[reg];
        }
#pragma unroll
        for (int nt = 0; nt < 4; nt++) {
            O[nt][0] *= alpha[0]; O[nt][1] *= alpha[1];
            O[nt][2] *= alpha[2]; O[nt][3] *= alpha[3];
        }

#pragma unroll
        for (int nt = 0; nt < 4; nt++)
#pragma unroll
            for (int reg = 0; reg < 4; reg++)
                Ps[(wave * 16 + quad * 4 + reg) * LDK + l15 + 16 * nt] = (bf16_t)S[nt][reg];

        bf16x8 pf0 = *(const bf16x8*)(Ps + (wave * 16 + l15) * LDK + quad * 8);
        bf16x8 pf1 = *(const bf16x8*)(Ps + (wave * 16 + l15) * LDK + 32 + quad * 8);
#pragma unroll
        for (int nt = 0; nt < 4; nt++) {
            bf16x8 vf0 = *(const bf16x8*)(VB + ((nt * 2 + 0) * 64 + lane) * 8);
            bf16x8 vf1 = *(const bf16x8*)(VB + ((nt * 2 + 1) * 64 + lane) * 8);
            O[nt] = mfma16(pf0, vf0, O[nt]);
            O[nt] = mfma16(pf1, vf1, O[nt]);
        }

#pragma unroll
        for (int reg = 0; reg < 4; reg++)
#pragma unroll
            for (int nt = 0; nt < 4; nt++)
                crel[reg][nt] = nrel[reg][nt];
    }

    float linv[4];
#pragma unroll
    for (int reg = 0; reg < 4; reg++) linv[reg] = 1.0f / l_i[reg];
#pragma unroll
    for (int nt = 0; nt < 4; nt++)
#pragma unroll
        for (int reg = 0; reg < 4; reg++) {
            int q = q0 + wave * 16 + quad * 4 + reg;
            attn_out[((size_t)q * BSZ + b) * ED + h * HD + l15 + 16 * nt] =
                (bf16_t)(O[nt][reg] * linv[reg]);
        }
}

// ------------------------------------------------------------------
extern "C" void kernel_launch(void* const* d_in, const int* in_sizes, int n_in,
                              void* d_out, int out_size, void* d_ws, size_t ws_size,
                              hipStream_t stream)
{
    const float* reg_x    = (const float*)d_in[0];
    const int*   sum_ids  = (const int*)d_in[1];
    const int*   rel_idx  = (const int*)d_in[2];
    const float* emb_sum  = (const float*)d_in[5];
    const float* rel_emb0 = (const float*)d_in[6];
    const float* Wq = (const float*)d_in[7];
    const float* bq = (const float*)d_in[8];
    const float* Wk = (const float*)d_in[9];
    const float* bk = (const float*)d_in[10];
    const float* Wv = (const float*)d_in[11];
    const float* bv = (const float*)d_in[12];
    const float* Wr0 = (const float*)d_in[13];
    const float* br0 = (const float*)d_in[14];
    const float* Wk2 = (const float*)d_in[15];
    const float* bk2 = (const float*)d_in[16];
    const float* Wv2 = (const float*)d_in[17];
    const float* bv2 = (const float*)d_in[18];
    const float* Wo  = (const float*)d_in[19];
    const float* bo  = (const float*)d_in[20];
    const float* ln_k_g  = (const float*)d_in[21];
    const float* ln_k_b  = (const float*)d_in[22];
    const float* ln_v_g  = (const float*)d_in[23];
    const float* ln_v_b  = (const float*)d_in[24];
    const float* ln_k2_g = (const float*)d_in[25];
    const float* ln_k2_b = (const float*)d_in[26];
    const float* ln_v2_g = (const float*)d_in[27];
    const float* ln_v2_b = (const float*)d_in[28];

    const size_t QKV = (size_t)BSZ * NH * RLEN * HD;   // 4,194,304
    const size_t SUM = (size_t)BSZ * NH * SLEN * HD;   // 131,072

    float* ws  = (float*)d_ws;
    float* k   = ws;                    // fp32 K; later aliased by aob
    float* v   = k + QKV;               // fp32 V
    float* r0  = v + QKV;
    float* sx2 = r0 + (size_t)NH * NZ * HD;

    bf16_t* xb   = (bf16_t*)(sx2 + SUM);   // dead after QKV gemm -> po
    bf16_t* qb   = xb + QKV;
    bf16_t* kfm  = qb + QKV;
    bf16_t* vfm  = kfm + QKV;
    bf16_t* sqb  = vfm + QKV;
    bf16_t* k2fm = sqb + SUM;
    bf16_t* v2fm = k2fm + SUM;
    bf16_t* wqt  = v2fm + SUM;          // wqt|wkt|wvt contiguous [3072][1024]
    bf16_t* wkt  = wqt + (size_t)ED * ED;
    bf16_t* wvt  = wkt + (size_t)ED * ED;
    bf16_t* wot  = wvt + (size_t)ED * ED;
    bf16_t* wr0t = wot + (size_t)ED * ED;
    bf16_t* re0b = wr0t + (size_t)ED * NZ;
    bf16_t* aob  = (bf16_t*)k;
    float*  po   = (float*)xb;
    float*  pm   = po + (size_t)BSZ * NH * NSPLIT * SLEN * HD;
    float*  pl   = pm + (size_t)BSZ * NH * NSPLIT * SLEN;

    const int M = RLEN * BSZ;   // 4096

    cvt_bf16<<<(int)(QKV / 1024), 256, 0, stream>>>(reg_x, xb, (int)QKV);
    cvt_bf16<<<4, 256, 0, stream>>>(rel_emb0, re0b, NZ * NZ);
    wt_batch<<<1040, 256, 0, stream>>>(Wq, Wk, Wv, Wo, Wr0, wqt, wkt, wvt, wot, wr0t);

    // fused QKV projection (m97-style)
    gemm_fast<128><<<dim3(3 * ED / 128, M / 128), 256, 0, stream>>>(
        xb, wqt, bq, bk, bv, qb, k, v, M, ED, 3 * ED, 1);

    ln_k_frag<<<(BSZ * NH * RLEN) / 4, 256, 0, stream>>>(k, ln_k_g, ln_k_b, kfm);
    lnv_frag<<<dim3(RLEN / 64, BSZ * NH), 256, 0, stream>>>(v, ln_v_g, ln_v_b, vfm);

    // r0 = rel_emb0 @ Wr0 -> fp32 [h][z][d]
    gemm_mfma<<<dim3(ED / 128, 1), 256, 0, stream>>>(re0b, wr0t, br0, r0, NZ, NZ, ED, NZ);

    sumq_gather<<<SLEN * BSZ, 256, 0, stream>>>(emb_sum, sum_ids, sqb);

    sum_attn_split<<<dim3(BSZ * NH, NSPLIT), 256, 0, stream>>>(sqb, kfm, vfm, r0, rel_idx, po, pm, pl);
    sum_reduce<<<dim3(BSZ * NH, 4), 256, 0, stream>>>(po, pm, pl, sx2);

    k2v2<<<BSZ * NH * SLEN, 64, 0, stream>>>(sx2, Wk2, bk2, Wv2, bv2,
                                             ln_k2_g, ln_k2_b, ln_v2_g, ln_v2_b, k2fm, v2fm);

    reg_attn_mfma<<<BSZ * NH * (RLEN / 64), 256, 0, stream>>>(qb, kfm, vfm, k2fm, v2fm,
                                                              r0, rel_idx, aob);

    // final projection -> d_out fp32 (R,B,E)
    gemm_fast<64><<<dim3(ED / 128, M / 64), 256, 0, stream>>>(
        aob, wot, bo, nullptr, nullptr, nullptr, (float*)d_out, nullptr, M, ED, ED, 0);
}

// Round 6
// 417.948 us; speedup vs baseline: 1.0980x; 1.0980x over previous
//
#include <hip/hip_runtime.h>
#include <cstdint>
#include <cstddef>

#define NH   16
#define HD   64
#define RLEN 2048
#define BSZ  2
#define SLEN 64
#define NZ   64
#define ED   1024
#define KTOT 2112   // SLEN + RLEN
#define NSPLIT 8    // sum_attn key splits

typedef __bf16 bf16_t;
typedef bf16_t bf16x8 __attribute__((ext_vector_type(8)));
typedef bf16_t bf16x4 __attribute__((ext_vector_type(4)));
typedef float  f32x4  __attribute__((ext_vector_type(4)));

__device__ __forceinline__ f32x4 mfma16(bf16x8 a, bf16x8 b, f32x4 c) {
    return __builtin_amdgcn_mfma_f32_16x16x32_bf16(a, b, c, 0, 0, 0);
}

// async global->LDS DMA, 16B per lane (used by gemm_fast only)
__device__ __forceinline__ void dma16(const void* g, void* l) {
    __builtin_amdgcn_global_load_lds(
        (const __attribute__((address_space(1))) unsigned int*)g,
        (__attribute__((address_space(3))) unsigned int*)l, 16, 0, 0);
}

// Frag-major K layout per bh (2048 keys x 64 d):
//   elem off = (((tile*4+nt)*2+kblk)*64 + quad*16 + l15)*8 + (d&7)
// Frag-major V^T: granule(dcol,key8): nt=d>>4, l15=d&15, kblk=key8>>2, quad=key8&3.

// ------------------------------------------------------------------
// m97-style GEMM: A bf16 [M][K], Bt bf16 [N][K]; BK=64, tile BM x 128,
// global_load_lds staging with XOR-swizzled granules.
// ------------------------------------------------------------------
template<int BM>
__global__ __launch_bounds__(256) void gemm_fast(
    const bf16_t* __restrict__ A, const bf16_t* __restrict__ Bt,
    const float* __restrict__ b0, const float* __restrict__ b1,
    const float* __restrict__ b2,
    bf16_t* __restrict__ oq, float* __restrict__ o1, float* __restrict__ o2,
    int M, int K, int N, int mode)
{
    constexpr int MT = BM / 64;
    __shared__ __align__(16) bf16_t As[BM * 64];
    __shared__ __align__(16) bf16_t Bs[128 * 64];

    const int t = threadIdx.x;
    const int wave = t >> 6, lane = t & 63;
    const int quad = lane >> 4, l15 = lane & 15;
    const int rsub = lane >> 3, gq = lane & 7;
    const int m0 = blockIdx.y * BM, n0 = blockIdx.x * 128;

    f32x4 acc[MT][8];
#pragma unroll
    for (int i = 0; i < MT; i++)
#pragma unroll
        for (int j = 0; j < 8; j++) acc[i][j] = (f32x4){0.f, 0.f, 0.f, 0.f};

    for (int k0 = 0; k0 < K; k0 += 64) {
#pragma unroll
        for (int j = 0; j < BM / 32; j++) {
            int row = wave * (BM / 4) + j * 8 + rsub;
            const bf16_t* g = A + (size_t)(m0 + row) * K + k0 + ((gq ^ (row & 7)) * 8);
            dma16(g, As + (wave * (BM / 4) + j * 8) * 64);
        }
#pragma unroll
        for (int j = 0; j < 4; j++) {
            int row = wave * 32 + j * 8 + rsub;
            const bf16_t* g = Bt + (size_t)(n0 + row) * K + k0 + ((gq ^ (row & 7)) * 8);
            dma16(g, Bs + (wave * 32 + j * 8) * 64);
        }
        __syncthreads();

#pragma unroll
        for (int kk = 0; kk < 2; kk++) {
            const int pg = ((kk * 4 + quad) ^ (l15 & 7)) * 8;
            bf16x8 af[MT], bf[8];
#pragma unroll
            for (int mt = 0; mt < MT; mt++)
                af[mt] = *(const bf16x8*)(As + (wave * (BM / 4) + mt * 16 + l15) * 64 + pg);
#pragma unroll
            for (int nt = 0; nt < 8; nt++)
                bf[nt] = *(const bf16x8*)(Bs + (nt * 16 + l15) * 64 + pg);
#pragma unroll
            for (int mt = 0; mt < MT; mt++)
#pragma unroll
                for (int nt = 0; nt < 8; nt++)
                    acc[mt][nt] = mfma16(af[mt], bf[nt], acc[mt][nt]);
        }
        __syncthreads();
    }

#pragma unroll
    for (int mt = 0; mt < MT; mt++)
#pragma unroll
        for (int nt = 0; nt < 8; nt++)
#pragma unroll
            for (int reg = 0; reg < 4; reg++) {
                int m = m0 + wave * (BM / 4) + mt * 16 + quad * 4 + reg;
                int n = n0 + nt * 16 + l15;
                if (mode == 0) {
                    o1[(size_t)m * N + n] = acc[mt][nt][reg] + b0[n];
                } else {
                    int seg = n >> 10, nl = n & 1023;
                    const float* bias = (seg == 0) ? b0 : (seg == 1) ? b1 : b2;
                    float c = acc[mt][nt][reg] + bias[nl];
                    int h = nl >> 6, d = nl & 63;
                    int r = m >> 1, bb = m & 1;
                    size_t off = (((size_t)bb * NH + h) * RLEN + r) * HD + d;
                    if (seg == 0)      oq[off] = (bf16_t)(c * 0.125f);
                    else if (seg == 1) o1[off] = c;
                    else               o2[off] = c;
                }
            }
}

// ------------------------------------------------------------------
// 64x128 MFMA GEMM (small r0 gemm only), padded LDS.
// ------------------------------------------------------------------
__global__ __launch_bounds__(256) void gemm_mfma(
    const bf16_t* __restrict__ A, const bf16_t* __restrict__ Bt,
    const float* __restrict__ bias, float* __restrict__ outf,
    int M, int K, int N, int Rr)
{
    constexpr int LDA = 40;
    __shared__ __align__(16) bf16_t As[64 * LDA];
    __shared__ __align__(16) bf16_t Bs[128 * LDA];

    const int t = threadIdx.x;
    const int wave = t >> 6, lane = t & 63;
    const int quad = lane >> 4, l15 = lane & 15;
    const int wrow = wave >> 1, wcol = wave & 1;
    const int m0 = blockIdx.y * 64, n0 = blockIdx.x * 128;

    f32x4 acc[2][4];
#pragma unroll
    for (int i = 0; i < 2; i++)
#pragma unroll
        for (int j = 0; j < 4; j++) acc[i][j] = (f32x4){0.f, 0.f, 0.f, 0.f};

    const int srow = t >> 2, sseg = (t & 3) * 8;

    for (int k0 = 0; k0 < K; k0 += 32) {
        bf16x8 av  = *(const bf16x8*)(A  + (size_t)(m0 + srow) * K + k0 + sseg);
        bf16x8 bv0 = *(const bf16x8*)(Bt + (size_t)(n0 + srow) * K + k0 + sseg);
        bf16x8 bv1 = *(const bf16x8*)(Bt + (size_t)(n0 + 64 + srow) * K + k0 + sseg);
        __syncthreads();
        *(bf16x8*)(As + srow * LDA + sseg)        = av;
        *(bf16x8*)(Bs + srow * LDA + sseg)        = bv0;
        *(bf16x8*)(Bs + (64 + srow) * LDA + sseg) = bv1;
        __syncthreads();

        bf16x8 af[2], bf[4];
#pragma unroll
        for (int mt = 0; mt < 2; mt++)
            af[mt] = *(const bf16x8*)(As + (wrow * 32 + mt * 16 + l15) * LDA + quad * 8);
#pragma unroll
        for (int nt = 0; nt < 4; nt++)
            bf[nt] = *(const bf16x8*)(Bs + (wcol * 64 + nt * 16 + l15) * LDA + quad * 8);
#pragma unroll
        for (int mt = 0; mt < 2; mt++)
#pragma unroll
            for (int nt = 0; nt < 4; nt++)
                acc[mt][nt] = mfma16(af[mt], bf[nt], acc[mt][nt]);
    }

#pragma unroll
    for (int mt = 0; mt < 2; mt++)
#pragma unroll
        for (int nt = 0; nt < 4; nt++)
#pragma unroll
            for (int reg = 0; reg < 4; reg++) {
                int m = m0 + wrow * 32 + mt * 16 + quad * 4 + reg;
                int n = n0 + wcol * 64 + nt * 16 + l15;
                if (m >= M) continue;
                float c = acc[mt][nt][reg] + bias[n];
                int h = n >> 6, d = n & 63;
                outf[(((size_t)h) * Rr + m) * HD + d] = c;   // [h][z][d]
            }
}

// ------------------------------------------------------------------
// K LayerNorm -> frag-major bf16. One wave per key row.
// ------------------------------------------------------------------
__global__ __launch_bounds__(256) void ln_k_frag(
    const float* __restrict__ x, const float* __restrict__ g, const float* __restrict__ b,
    bf16_t* __restrict__ kfm)
{
    int row  = blockIdx.x * 4 + (threadIdx.x >> 6);
    int lane = threadIdx.x & 63;
    float v = x[(size_t)row * HD + lane];
    float s1 = v, s2 = v * v;
#pragma unroll
    for (int o = 32; o > 0; o >>= 1) {
        s1 += __shfl_xor(s1, o);
        s2 += __shfl_xor(s2, o);
    }
    float mean = s1 * (1.f / 64.f);
    float var  = s2 * (1.f / 64.f) - mean * mean;
    float y = (v - mean) * rsqrtf(var + 1e-5f) * g[lane] + b[lane];
    int bh = row >> 11, r = row & 2047, d = lane;
    size_t off = (size_t)bh * 131072 +
        (size_t)(((((r >> 6) * 4 + ((r >> 4) & 3)) * 2 + (d >> 5)) * 64
                  + ((d >> 3) & 3) * 16 + (r & 15)) * 8 + (d & 7));
    kfm[off] = (bf16_t)y;
}

// ------------------------------------------------------------------
// V LayerNorm + transpose -> frag-major bf16 V^T. grid (RLEN/64, BSZ*NH).
// ------------------------------------------------------------------
__global__ __launch_bounds__(256) void lnv_frag(
    const float* __restrict__ v, const float* __restrict__ g,
    const float* __restrict__ b, bf16_t* __restrict__ vfm)
{
    __shared__ float tile[64][65];
    const int bh = blockIdx.y, tidx = blockIdx.x;
    const int t = threadIdx.x;
    const int wave = t >> 6, lane = t & 63;

#pragma unroll
    for (int i = 0; i < 16; i++) {
        int rl = wave * 16 + i;
        float x = v[((size_t)bh * RLEN + tidx * 64 + rl) * HD + lane];
        float s1 = x, s2 = x * x;
#pragma unroll
        for (int o = 32; o > 0; o >>= 1) {
            s1 += __shfl_xor(s1, o);
            s2 += __shfl_xor(s2, o);
        }
        float mean = s1 * (1.f / 64.f);
        float var  = s2 * (1.f / 64.f) - mean * mean;
        tile[rl][lane] = (x - mean) * rsqrtf(var + 1e-5f) * g[lane] + b[lane];
    }
    __syncthreads();
    int d = t >> 2, rs = (t & 3) * 16;
    bf16x8 o0, o1;
#pragma unroll
    for (int j = 0; j < 8; j++) {
        o0[j] = (bf16_t)tile[rs + j][d];
        o1[j] = (bf16_t)tile[rs + 8 + j][d];
    }
    size_t base = (size_t)bh * 131072;
    size_t off0 = base + (size_t)((((tidx * 4 + (d >> 4)) * 2 + (rs >> 5)) * 64
                  + ((rs >> 3) & 3) * 16 + (d & 15)) * 8);
    int rs2 = rs + 8;
    size_t off1 = base + (size_t)((((tidx * 4 + (d >> 4)) * 2 + (rs2 >> 5)) * 64
                  + ((rs2 >> 3) & 3) * 16 + (d & 15)) * 8);
    *(bf16x8*)(vfm + off0) = o0;
    *(bf16x8*)(vfm + off1) = o1;
}

// ------------------------------------------------------------------
__global__ __launch_bounds__(256) void cvt_bf16(
    const float* __restrict__ src, bf16_t* __restrict__ dst, int n)
{
    int i = (blockIdx.x * 256 + threadIdx.x) * 4;
    if (i < n) {
        float4 v = *(const float4*)(src + i);
        bf16x4 o;
        o[0] = (bf16_t)v.x; o[1] = (bf16_t)v.y; o[2] = (bf16_t)v.z; o[3] = (bf16_t)v.w;
        *(bf16x4*)(dst + i) = o;
    }
}

// ------------------------------------------------------------------
// Batched weight transpose+cvt -> [n][k] bf16.
// ------------------------------------------------------------------
__global__ __launch_bounds__(256) void wt_batch(
    const float* __restrict__ Wq, const float* __restrict__ Wk,
    const float* __restrict__ Wv, const float* __restrict__ Wo,
    const float* __restrict__ Wr0,
    bf16_t* __restrict__ wqt, bf16_t* __restrict__ wkt,
    bf16_t* __restrict__ wvt, bf16_t* __restrict__ wot,
    bf16_t* __restrict__ wr0t)
{
    __shared__ float tile[64][65];
    const int bid = blockIdx.x;
    const float* src; bf16_t* dst; int R, C, r0, c0;
    if (bid < 1024) {
        int sel = bid >> 8, local = bid & 255;
        src = (sel == 0) ? Wq : (sel == 1) ? Wk : (sel == 2) ? Wv : Wo;
        dst = (sel == 0) ? wqt : (sel == 1) ? wkt : (sel == 2) ? wvt : wot;
        R = ED; C = ED; r0 = (local >> 4) * 64; c0 = (local & 15) * 64;
    } else {
        src = Wr0; dst = wr0t; R = NZ; C = ED; r0 = 0; c0 = (bid - 1024) * 64;
    }
    const int t = threadIdx.x;
#pragma unroll
    for (int i = 0; i < 4; i++) {
        int idx = t + i * 256;
        int r = idx >> 4, c = (idx & 15) * 4;
        float4 vv = *(const float4*)(src + (size_t)(r0 + r) * C + c0 + c);
        tile[r][c] = vv.x; tile[r][c + 1] = vv.y; tile[r][c + 2] = vv.z; tile[r][c + 3] = vv.w;
    }
    __syncthreads();
    int cc = t >> 2, rs = (t & 3) * 16;
    bf16x8 o0, o1;
#pragma unroll
    for (int j = 0; j < 8; j++) {
        o0[j] = (bf16_t)tile[rs + j][cc];
        o1[j] = (bf16_t)tile[rs + 8 + j][cc];
    }
    *(bf16x8*)(dst + (size_t)(c0 + cc) * R + r0 + rs) = o0;
    *(bf16x8*)(dst + (size_t)(c0 + cc) * R + r0 + rs + 8) = o1;
}

// ------------------------------------------------------------------
__global__ __launch_bounds__(256) void sumq_gather(
    const float* __restrict__ emb, const int* __restrict__ ids,
    bf16_t* __restrict__ sum_q)
{
    int sb = blockIdx.x;
    int s = sb >> 1, b = sb & 1;
    int id = ids[b * SLEN + s];
    const float* src = emb + (size_t)id * ED;
    for (int e = threadIdx.x; e < ED; e += 256) {
        int h = e >> 6, d = e & 63;
        sum_q[(((size_t)b * NH + h) * SLEN + s) * HD + d] = (bf16_t)(src[e] * 0.125f);
    }
}

// ------------------------------------------------------------------
// Summary attention, split-K, BARRIER-FREE: each wave owns 16 s-rows,
// streams its 4 key-tiles global->reg (frag-major). grid (32, NSPLIT).
// ------------------------------------------------------------------
__global__ __launch_bounds__(256) void sum_attn_split(
    const bf16_t* __restrict__ Qb,   // sum_q [bh][s][d] row-major
    const bf16_t* __restrict__ kfm, const bf16_t* __restrict__ vfm,
    const float*  __restrict__ r0,
    const int*    __restrict__ rel_idx,
    float* __restrict__ po, float* __restrict__ pm, float* __restrict__ pl)
{
    const int bh = blockIdx.x;
    const int split = blockIdx.y;
    const int b = bh >> 4, h = bh & 15;
    const int t = threadIdx.x;
    const int wave = t >> 6, lane = t & 63;
    const int quad = lane >> 4, l15 = lane & 15;

    __shared__ __align__(16) bf16_t Ps[4][16 * 72];
    __shared__ __align__(16) bf16_t qrs[4][16 * 64];

    const bf16_t* Qrow = Qb + ((size_t)bh * SLEN + wave * 16 + l15) * HD;
    bf16x8 qf0 = *(const bf16x8*)(Qrow + quad * 8);
    bf16x8 qf1 = *(const bf16x8*)(Qrow + 32 + quad * 8);

#pragma unroll
    for (int nt = 0; nt < 4; nt++) {
        f32x4 qa = {0.f, 0.f, 0.f, 0.f};
        const float* rp = r0 + ((size_t)h * NZ + l15 + 16 * nt) * HD + quad * 8;
        float4 a0 = *(const float4*)(rp);
        float4 a1 = *(const float4*)(rp + 4);
        bf16x8 bf;
        bf[0] = (bf16_t)a0.x; bf[1] = (bf16_t)a0.y; bf[2] = (bf16_t)a0.z; bf[3] = (bf16_t)a0.w;
        bf[4] = (bf16_t)a1.x; bf[5] = (bf16_t)a1.y; bf[6] = (bf16_t)a1.z; bf[7] = (bf16_t)a1.w;
        qa = mfma16(qf0, bf, qa);
        float4 b0 = *(const float4*)(rp + 32);
        float4 b1 = *(const float4*)(rp + 36);
        bf[0] = (bf16_t)b0.x; bf[1] = (bf16_t)b0.y; bf[2] = (bf16_t)b0.z; bf[3] = (bf16_t)b0.w;
        bf[4] = (bf16_t)b1.x; bf[5] = (bf16_t)b1.y; bf[6] = (bf16_t)b1.z; bf[7] = (bf16_t)b1.w;
        qa = mfma16(qf1, bf, qa);
#pragma unroll
        for (int reg = 0; reg < 4; reg++)
            qrs[wave][(quad * 4 + reg) * 64 + l15 + 16 * nt] = (bf16_t)qa[reg];
    }

    f32x4 O[4];
    float m_i[4], l_i[4];
#pragma unroll
    for (int nt = 0; nt < 4; nt++) O[nt] = (f32x4){0.f, 0.f, 0.f, 0.f};
#pragma unroll
    for (int r = 0; r < 4; r++) { m_i[r] = -1e30f; l_i[r] = 0.f; }

    const int* relp[4];
#pragma unroll
    for (int reg = 0; reg < 4; reg++)
        relp[reg] = rel_idx + ((size_t)b * KTOT + wave * 16 + quad * 4 + reg) * RLEN + l15;

    for (int i = 0; i < 4; i++) {
        const int tile = split * 4 + i;
        const bf16_t* kt = kfm + (size_t)bh * 131072 + (size_t)tile * 4096;
        const bf16_t* vt = vfm + (size_t)bh * 131072 + (size_t)tile * 4096;

        bf16x8 kf[4][2];
#pragma unroll
        for (int nt = 0; nt < 4; nt++)
#pragma unroll
            for (int kb = 0; kb < 2; kb++)
                kf[nt][kb] = *(const bf16x8*)(kt + ((nt * 2 + kb) * 64 + lane) * 8);
        int crel[4][4];
#pragma unroll
        for (int reg = 0; reg < 4; reg++)
#pragma unroll
            for (int nt = 0; nt < 4; nt++)
                crel[reg][nt] = relp[reg][tile * 64 + 16 * nt];

        f32x4 S[4];
#pragma unroll
        for (int nt = 0; nt < 4; nt++) {
            f32x4 acc = {0.f, 0.f, 0.f, 0.f};
            acc = mfma16(qf0, kf[nt][0], acc);
            acc = mfma16(qf1, kf[nt][1], acc);
            S[nt] = acc;
        }

        bf16x8 vf[4][2];
#pragma unroll
        for (int nt = 0; nt < 4; nt++)
#pragma unroll
            for (int kb = 0; kb < 2; kb++)
                vf[nt][kb] = *(const bf16x8*)(vt + ((nt * 2 + kb) * 64 + lane) * 8);

#pragma unroll
        for (int reg = 0; reg < 4; reg++) {
            int ql = quad * 4 + reg;
#pragma unroll
            for (int nt = 0; nt < 4; nt++)
                S[nt][reg] += (float)qrs[wave][ql * 64 + crel[reg][nt]];
        }

        float tmax[4];
#pragma unroll
        for (int reg = 0; reg < 4; reg++) {
            float v = fmaxf(fmaxf(S[0][reg], S[1][reg]), fmaxf(S[2][reg], S[3][reg]));
#pragma unroll
            for (int o = 8; o > 0; o >>= 1) v = fmaxf(v, __shfl_xor(v, o));
            tmax[reg] = v;
        }
        float alpha[4], psum[4];
#pragma unroll
        for (int reg = 0; reg < 4; reg++) {
            float mn = fmaxf(m_i[reg], tmax[reg]);
            alpha[reg] = __expf(m_i[reg] - mn);
            m_i[reg] = mn;
            psum[reg] = 0.f;
        }
#pragma unroll
        for (int nt = 0; nt < 4; nt++)
#pragma unroll
            for (int reg = 0; reg < 4; reg++) {
                float p = __expf(S[nt][reg] - m_i[reg]);
                S[nt][reg] = p;
                psum[reg] += p;
            }
#pragma unroll
        for (int reg = 0; reg < 4; reg++) {
#pragma unroll
            for (int o = 8; o > 0; o >>= 1) psum[reg] += __shfl_xor(psum[reg], o);
            l_i[reg] = l_i[reg] * alpha[reg] + psum[reg];
        }
#pragma unroll
        for (int nt = 0; nt < 4; nt++) {
            O[nt][0] *= alpha[0]; O[nt][1] *= alpha[1];
            O[nt][2] *= alpha[2]; O[nt][3] *= alpha[3];
        }

#pragma unroll
        for (int nt = 0; nt < 4; nt++)
#pragma unroll
            for (int reg = 0; reg < 4; reg++)
                Ps[wave][(quad * 4 + reg) * 72 + l15 + 16 * nt] = (bf16_t)S[nt][reg];

        bf16x8 pf0 = *(const bf16x8*)(Ps[wave] + l15 * 72 + quad * 8);
        bf16x8 pf1 = *(const bf16x8*)(Ps[wave] + l15 * 72 + 32 + quad * 8);
#pragma unroll
        for (int nt = 0; nt < 4; nt++) {
            O[nt] = mfma16(pf0, vf[nt][0], O[nt]);
            O[nt] = mfma16(pf1, vf[nt][1], O[nt]);
        }
    }

    const size_t pslot = (size_t)bh * NSPLIT + split;
#pragma unroll
    for (int nt = 0; nt < 4; nt++)
#pragma unroll
        for (int reg = 0; reg < 4; reg++) {
            int sq = wave * 16 + quad * 4 + reg;
            po[(pslot * SLEN + sq) * HD + l15 + 16 * nt] = O[nt][reg];
        }
#pragma unroll
    for (int reg = 0; reg < 4; reg++) {
        int sq = wave * 16 + quad * 4 + reg;
        if (l15 == 0) {
            pm[pslot * SLEN + sq] = m_i[reg];
            pl[pslot * SLEN + sq] = l_i[reg];
        }
    }
}

// ------------------------------------------------------------------
__global__ __launch_bounds__(256) void sum_reduce(
    const float* __restrict__ po, const float* __restrict__ pm,
    const float* __restrict__ pl, float* __restrict__ sum_x2)
{
    const int bh = blockIdx.x;
    const int sg0 = blockIdx.y * 16;
    const int t = threadIdx.x;
    const int d = t & 63, si = t >> 6;
#pragma unroll
    for (int i = 0; i < 4; i++) {
        int s = sg0 + si * 4 + i;
        float M = -1e30f, mm[NSPLIT];
#pragma unroll
        for (int j = 0; j < NSPLIT; j++) {
            mm[j] = pm[((size_t)bh * NSPLIT + j) * SLEN + s];
            M = fmaxf(M, mm[j]);
        }
        float L = 0.f, acc = 0.f;
#pragma unroll
        for (int j = 0; j < NSPLIT; j++) {
            float a = __expf(mm[j] - M);
            L += pl[((size_t)bh * NSPLIT + j) * SLEN + s] * a;
            acc += po[(((size_t)bh * NSPLIT + j) * SLEN + s) * HD + d] * a;
        }
        sum_x2[((size_t)bh * SLEN + s) * HD + d] = acc / L;
    }
}

// ------------------------------------------------------------------
// sum_k2 / sum_v2: y = LN(x @ W + b); write frag-major bf16 single tile.
// ------------------------------------------------------------------
__global__ __launch_bounds__(64) void k2v2(
    const float* __restrict__ sum_x2,
    const float* __restrict__ Wk2, const float* __restrict__ bk2,
    const float* __restrict__ Wv2, const float* __restrict__ bv2,
    const float* __restrict__ gk, const float* __restrict__ bk,
    const float* __restrict__ gv, const float* __restrict__ bv,
    bf16_t* __restrict__ k2fm, bf16_t* __restrict__ v2fm)
{
    int row = blockIdx.x;              // bh*64 + s
    int d = threadIdx.x;
    int bh = row >> 6, s = row & 63;
    __shared__ float xs[64];
    xs[d] = sum_x2[(size_t)row * HD + d];
    __syncthreads();

#pragma unroll
    for (int which = 0; which < 2; which++) {
        const float* W  = which ? Wv2 : Wk2;
        const float* bi = which ? bv2 : bk2;
        const float* g  = which ? gv : gk;
        const float* bb = which ? bv : bk;
        float a = bi[d];
#pragma unroll
        for (int j = 0; j < 64; j++) a += xs[j] * W[j * HD + d];
        float s1 = a, s2 = a * a;
#pragma unroll
        for (int o = 32; o > 0; o >>= 1) {
            s1 += __shfl_xor(s1, o);
            s2 += __shfl_xor(s2, o);
        }
        float mean = s1 * (1.f / 64.f);
        float var  = s2 * (1.f / 64.f) - mean * mean;
        float y = (a - mean) * rsqrtf(var + 1e-5f) * g[d] + bb[d];
        if (which == 0) {
            size_t off = (size_t)bh * 4096 +
                (size_t)(((((s >> 4) & 3) * 2 + (d >> 5)) * 64
                          + ((d >> 3) & 3) * 16 + (s & 15)) * 8 + (d & 7));
            k2fm[off] = (bf16_t)y;
        } else {
            size_t off = (size_t)bh * 4096 +
                (size_t)((((d >> 4) * 2 + (s >> 5)) * 64
                          + ((s >> 3) & 3) * 16 + (d & 15)) * 8 + (s & 7));
            v2fm[off] = (bf16_t)y;
        }
    }
}

// ------------------------------------------------------------------
// Main attention, BARRIER-FREE MFMA flash: each wave owns 32 q-rows
// (2 m-frags), streams all 33 key-tiles global->reg (frag-major K/V).
// Wave-private LDS only (qr table + P round-trip) — zero __syncthreads
// in the K-loop. Block = (bh, 128-q tile), 4 waves. grid 512.
// ------------------------------------------------------------------
__global__ __launch_bounds__(256) void reg_attn_mfma(
    const bf16_t* __restrict__ Qb,    // [bh][r][d] row-major
    const bf16_t* __restrict__ kfm, const bf16_t* __restrict__ vfm,
    const bf16_t* __restrict__ k2fm, const bf16_t* __restrict__ v2fm,
    const float*  __restrict__ r0,
    const int*    __restrict__ rel_idx,
    bf16_t* __restrict__ attn_out)    // [r][b][E] bf16
{
    const int bid = blockIdx.x;       // 512 = 8 XCD-groups x 4 bh x 16 qtiles
    const int bh = (bid & 7) * 4 + ((bid >> 3) & 3);
    const int qt = bid >> 5;          // 0..15
    const int b = bh >> 4, h = bh & 15;
    const int q0 = qt * 128;

    const int t = threadIdx.x;
    const int wave = t >> 6, lane = t & 63;
    const int quad = lane >> 4, l15 = lane & 15;

    __shared__ __align__(16) bf16_t Ps[4][32 * 72];
    __shared__ __align__(16) bf16_t qrs[4][32 * 64];

    // Q fragments: 2 m-frags x 2 k-halves
    bf16x8 qf[2][2];
#pragma unroll
    for (int mt = 0; mt < 2; mt++) {
        const bf16_t* Qrow = Qb + ((size_t)bh * RLEN + q0 + wave * 32 + mt * 16 + l15) * HD;
        qf[mt][0] = *(const bf16x8*)(Qrow + quad * 8);
        qf[mt][1] = *(const bf16x8*)(Qrow + 32 + quad * 8);
    }

    // qr table (wave-private): rows mt*16+quad*4+reg, cols z
#pragma unroll
    for (int nt = 0; nt < 4; nt++) {
        const float* rp = r0 + ((size_t)h * NZ + l15 + 16 * nt) * HD + quad * 8;
        float4 a0 = *(const float4*)(rp);
        float4 a1 = *(const float4*)(rp + 4);
        bf16x8 bf0;
        bf0[0] = (bf16_t)a0.x; bf0[1] = (bf16_t)a0.y; bf0[2] = (bf16_t)a0.z; bf0[3] = (bf16_t)a0.w;
        bf0[4] = (bf16_t)a1.x; bf0[5] = (bf16_t)a1.y; bf0[6] = (bf16_t)a1.z; bf0[7] = (bf16_t)a1.w;
        float4 b0 = *(const float4*)(rp + 32);
        float4 b1 = *(const float4*)(rp + 36);
        bf16x8 bf1;
        bf1[0] = (bf16_t)b0.x; bf1[1] = (bf16_t)b0.y; bf1[2] = (bf16_t)b0.z; bf1[3] = (bf16_t)b0.w;
        bf1[4] = (bf16_t)b1.x; bf1[5] = (bf16_t)b1.y; bf1[6] = (bf16_t)b1.z; bf1[7] = (bf16_t)b1.w;
#pragma unroll
        for (int mt = 0; mt < 2; mt++) {
            f32x4 qa = {0.f, 0.f, 0.f, 0.f};
            qa = mfma16(qf[mt][0], bf0, qa);
            qa = mfma16(qf[mt][1], bf1, qa);
#pragma unroll
            for (int reg = 0; reg < 4; reg++)
                qrs[wave][(mt * 16 + quad * 4 + reg) * 64 + l15 + 16 * nt] = (bf16_t)qa[reg];
        }
    }

    f32x4 O[2][4];
    float m_i[2][4], l_i[2][4];
#pragma unroll
    for (int mt = 0; mt < 2; mt++)
#pragma unroll
        for (int nt = 0; nt < 4; nt++) O[mt][nt] = (f32x4){0.f, 0.f, 0.f, 0.f};
#pragma unroll
    for (int mt = 0; mt < 2; mt++)
#pragma unroll
        for (int r = 0; r < 4; r++) { m_i[mt][r] = -1e30f; l_i[mt][r] = 0.f; }

    const int* relp[2][4];
#pragma unroll
    for (int mt = 0; mt < 2; mt++)
#pragma unroll
        for (int reg = 0; reg < 4; reg++)
            relp[mt][reg] = rel_idx +
                ((size_t)b * KTOT + SLEN + q0 + wave * 32 + mt * 16 + quad * 4 + reg) * RLEN + l15;

    const bf16_t* kbase = kfm + (size_t)bh * 131072;
    const bf16_t* vbase = vfm + (size_t)bh * 131072;

    for (int tile = 0; tile < 33; tile++) {
        const bf16_t* kt; const bf16_t* vt;
        if (tile == 0) {
            kt = k2fm + (size_t)bh * 4096;
            vt = v2fm + (size_t)bh * 4096;
        } else {
            kt = kbase + (size_t)(tile - 1) * 4096;
            vt = vbase + (size_t)(tile - 1) * 4096;
        }

        // K frags + rel ints (issued first; consumed below)
        bf16x8 kf[4][2];
#pragma unroll
        for (int nt = 0; nt < 4; nt++)
#pragma unroll
            for (int kb = 0; kb < 2; kb++)
                kf[nt][kb] = *(const bf16x8*)(kt + ((nt * 2 + kb) * 64 + lane) * 8);
        int crel[2][4][4];
        if (tile > 0) {
#pragma unroll
            for (int mt = 0; mt < 2; mt++)
#pragma unroll
                for (int reg = 0; reg < 4; reg++)
#pragma unroll
                    for (int nt = 0; nt < 4; nt++)
                        crel[mt][reg][nt] = relp[mt][reg][(tile - 1) * 64 + 16 * nt];
        }

        // S = Q K^T
        f32x4 S[2][4];
#pragma unroll
        for (int mt = 0; mt < 2; mt++)
#pragma unroll
            for (int nt = 0; nt < 4; nt++) {
                f32x4 acc = {0.f, 0.f, 0.f, 0.f};
                acc = mfma16(qf[mt][0], kf[nt][0], acc);
                acc = mfma16(qf[mt][1], kf[nt][1], acc);
                S[mt][nt] = acc;
            }

        // V frags issued now (K regs dead) — latency hides under softmax
        bf16x8 vf[4][2];
#pragma unroll
        for (int nt = 0; nt < 4; nt++)
#pragma unroll
            for (int kb = 0; kb < 2; kb++)
                vf[nt][kb] = *(const bf16x8*)(vt + ((nt * 2 + kb) * 64 + lane) * 8);

        // rel bias
        if (tile > 0) {
#pragma unroll
            for (int mt = 0; mt < 2; mt++)
#pragma unroll
                for (int reg = 0; reg < 4; reg++) {
                    int ql = mt * 16 + quad * 4 + reg;
#pragma unroll
                    for (int nt = 0; nt < 4; nt++)
                        S[mt][nt][reg] += (float)qrs[wave][ql * 64 + crel[mt][reg][nt]];
                }
        }

        // online softmax per m-frag
#pragma unroll
        for (int mt = 0; mt < 2; mt++) {
            float tmax[4];
#pragma unroll
            for (int reg = 0; reg < 4; reg++) {
                float v = fmaxf(fmaxf(S[mt][0][reg], S[mt][1][reg]),
                                fmaxf(S[mt][2][reg], S[mt][3][reg]));
#pragma unroll
                for (int o = 8; o > 0; o >>= 1) v = fmaxf(v, __shfl_xor(v, o));
                tmax[reg] = v;
            }
            float alpha[4], psum[4];
#pragma unroll
            for (int reg = 0; reg < 4; reg++) {
                float mn = fmaxf(m_i[mt][reg], tmax[reg]);
                alpha[reg] = __expf(m_i[mt][reg] - mn);
                m_i[mt][reg] = mn;
                psum[reg] = 0.f;
            }
#pragma unroll
            for (int nt = 0; nt < 4; nt++)
#pragma unroll
                for (int reg = 0; reg < 4; reg++) {
                    float p = __expf(S[mt][nt][reg] - m_i[mt][reg]);
                    S[mt][nt][reg] = p;
                    psum[reg] += p;
                }
#pragma unroll
            for (int reg = 0; reg < 4; reg++) {
#pragma unroll
                for (int o = 8; o > 0; o >>= 1) psum[reg] += __shfl_xor(psum[reg], o);
                l_i[mt][reg] = l_i[mt][reg] * alpha[reg] + psum[reg];
            }
#pragma unroll
            for (int nt = 0; nt < 4; nt++) {
                O[mt][nt][0] *= alpha[0]; O[mt][nt][1] *= alpha[1];
                O[mt][nt][2] *= alpha[2]; O[mt][nt][3] *= alpha[3];
            }
        }

        // P -> wave-private LDS strip, then PV (no barrier needed)
#pragma unroll
        for (int mt = 0; mt < 2; mt++)
#pragma unroll
            for (int nt = 0; nt < 4; nt++)
#pragma unroll
                for (int reg = 0; reg < 4; reg++)
                    Ps[wave][(mt * 16 + quad * 4 + reg) * 72 + l15 + 16 * nt] =
                        (bf16_t)S[mt][nt][reg];

#pragma unroll
        for (int mt = 0; mt < 2; mt++) {
            bf16x8 pf0 = *(const bf16x8*)(Ps[wave] + (mt * 16 + l15) * 72 + quad * 8);
            bf16x8 pf1 = *(const bf16x8*)(Ps[wave] + (mt * 16 + l15) * 72 + 32 + quad * 8);
#pragma unroll
            for (int nt = 0; nt < 4; nt++) {
                O[mt][nt] = mfma16(pf0, vf[nt][0], O[mt][nt]);
                O[mt][nt] = mfma16(pf1, vf[nt][1], O[mt][nt]);
            }
        }
    }

    // epilogue
#pragma unroll
    for (int mt = 0; mt < 2; mt++) {
        float linv[4];
#pragma unroll
        for (int reg = 0; reg < 4; reg++) linv[reg] = 1.0f / l_i[mt][reg];
#pragma unroll
        for (int nt = 0; nt < 4; nt++)
#pragma unroll
            for (int reg = 0; reg < 4; reg++) {
                int q = q0 + wave * 32 + mt * 16 + quad * 4 + reg;
                attn_out[((size_t)q * BSZ + b) * ED + h * HD + l15 + 16 * nt] =
                    (bf16_t)(O[mt][nt][reg] * linv[reg]);
            }
    }
}

// ------------------------------------------------------------------
extern "C" void kernel_launch(void* const* d_in, const int* in_sizes, int n_in,
                              void* d_out, int out_size, void* d_ws, size_t ws_size,
                              hipStream_t stream)
{
    const float* reg_x    = (const float*)d_in[0];
    const int*   sum_ids  = (const int*)d_in[1];
    const int*   rel_idx  = (const int*)d_in[2];
    const float* emb_sum  = (const float*)d_in[5];
    const float* rel_emb0 = (const float*)d_in[6];
    const float* Wq = (const float*)d_in[7];
    const float* bq = (const float*)d_in[8];
    const float* Wk = (const float*)d_in[9];
    const float* bk = (const float*)d_in[10];
    const float* Wv = (const float*)d_in[11];
    const float* bv = (const float*)d_in[12];
    const float* Wr0 = (const float*)d_in[13];
    const float* br0 = (const float*)d_in[14];
    const float* Wk2 = (const float*)d_in[15];
    const float* bk2 = (const float*)d_in[16];
    const float* Wv2 = (const float*)d_in[17];
    const float* bv2 = (const float*)d_in[18];
    const float* Wo  = (const float*)d_in[19];
    const float* bo  = (const float*)d_in[20];
    const float* ln_k_g  = (const float*)d_in[21];
    const float* ln_k_b  = (const float*)d_in[22];
    const float* ln_v_g  = (const float*)d_in[23];
    const float* ln_v_b  = (const float*)d_in[24];
    const float* ln_k2_g = (const float*)d_in[25];
    const float* ln_k2_b = (const float*)d_in[26];
    const float* ln_v2_g = (const float*)d_in[27];
    const float* ln_v2_b = (const float*)d_in[28];

    const size_t QKV = (size_t)BSZ * NH * RLEN * HD;   // 4,194,304
    const size_t SUM = (size_t)BSZ * NH * SLEN * HD;   // 131,072

    float* ws  = (float*)d_ws;
    float* k   = ws;                    // fp32 K; later aliased by aob
    float* v   = k + QKV;               // fp32 V
    float* r0  = v + QKV;
    float* sx2 = r0 + (size_t)NH * NZ * HD;

    bf16_t* xb   = (bf16_t*)(sx2 + SUM);   // dead after QKV gemm -> po
    bf16_t* qb   = xb + QKV;
    bf16_t* kfm  = qb + QKV;
    bf16_t* vfm  = kfm + QKV;
    bf16_t* sqb  = vfm + QKV;
    bf16_t* k2fm = sqb + SUM;
    bf16_t* v2fm = k2fm + SUM;
    bf16_t* wqt  = v2fm + SUM;          // wqt|wkt|wvt contiguous [3072][1024]
    bf16_t* wkt  = wqt + (size_t)ED * ED;
    bf16_t* wvt  = wkt + (size_t)ED * ED;
    bf16_t* wot  = wvt + (size_t)ED * ED;
    bf16_t* wr0t = wot + (size_t)ED * ED;
    bf16_t* re0b = wr0t + (size_t)ED * NZ;
    bf16_t* aob  = (bf16_t*)k;
    float*  po   = (float*)xb;
    float*  pm   = po + (size_t)BSZ * NH * NSPLIT * SLEN * HD;
    float*  pl   = pm + (size_t)BSZ * NH * NSPLIT * SLEN;

    const int M = RLEN * BSZ;   // 4096

    cvt_bf16<<<(int)(QKV / 1024), 256, 0, stream>>>(reg_x, xb, (int)QKV);
    cvt_bf16<<<4, 256, 0, stream>>>(rel_emb0, re0b, NZ * NZ);
    wt_batch<<<1040, 256, 0, stream>>>(Wq, Wk, Wv, Wo, Wr0, wqt, wkt, wvt, wot, wr0t);

    gemm_fast<128><<<dim3(3 * ED / 128, M / 128), 256, 0, stream>>>(
        xb, wqt, bq, bk, bv, qb, k, v, M, ED, 3 * ED, 1);

    ln_k_frag<<<(BSZ * NH * RLEN) / 4, 256, 0, stream>>>(k, ln_k_g, ln_k_b, kfm);
    lnv_frag<<<dim3(RLEN / 64, BSZ * NH), 256, 0, stream>>>(v, ln_v_g, ln_v_b, vfm);

    gemm_mfma<<<dim3(ED / 128, 1), 256, 0, stream>>>(re0b, wr0t, br0, r0, NZ, NZ, ED, NZ);

    sumq_gather<<<SLEN * BSZ, 256, 0, stream>>>(emb_sum, sum_ids, sqb);

    sum_attn_split<<<dim3(BSZ * NH, NSPLIT), 256, 0, stream>>>(sqb, kfm, vfm, r0, rel_idx, po, pm, pl);
    sum_reduce<<<dim3(BSZ * NH, 4), 256, 0, stream>>>(po, pm, pl, sx2);

    k2v2<<<BSZ * NH * SLEN, 64, 0, stream>>>(sx2, Wk2, bk2, Wv2, bv2,
                                             ln_k2_g, ln_k2_b, ln_v2_g, ln_v2_b, k2fm, v2fm);

    reg_attn_mfma<<<512, 256, 0, stream>>>(qb, kfm, vfm, k2fm, v2fm, r0, rel_idx, aob);

    gemm_fast<64><<<dim3(ED / 128, M / 64), 256, 0, stream>>>(
        aob, wot, bo, nullptr, nullptr, nullptr, (float*)d_out, nullptr, M, ED, ED, 0);
}

// Round 7
// 417.570 us; speedup vs baseline: 1.0989x; 1.0009x over previous
//
#include <hip/hip_runtime.h>
#include <cstdint>
#include <cstddef>

#define NH   16
#define HD   64
#define RLEN 2048
#define BSZ  2
#define SLEN 64
#define NZ   64
#define ED   1024
#define KTOT 2112   // SLEN + RLEN
#define NSPLIT 8    // sum_attn key splits

typedef __bf16 bf16_t;
typedef bf16_t bf16x8 __attribute__((ext_vector_type(8)));
typedef bf16_t bf16x4 __attribute__((ext_vector_type(4)));
typedef float  f32x4  __attribute__((ext_vector_type(4)));

__device__ __forceinline__ f32x4 mfma16(bf16x8 a, bf16x8 b, f32x4 c) {
    return __builtin_amdgcn_mfma_f32_16x16x32_bf16(a, b, c, 0, 0, 0);
}

// async global->LDS DMA, 16B per lane (used by gemm_fast only)
__device__ __forceinline__ void dma16(const void* g, void* l) {
    __builtin_amdgcn_global_load_lds(
        (const __attribute__((address_space(1))) unsigned int*)g,
        (__attribute__((address_space(3))) unsigned int*)l, 16, 0, 0);
}

// Frag-major K layout per bh (PERMUTED keys: within a 64-key tile, MFMA
// group nt holds keys {4*l15+nt}):
//   off(key,d) = tile*4096 + (((key&3)*2 + (d>>5))*64 + ((d>>3)&3)*16 + ((key>>2)&15))*8 + (d&7)
// Frag-major V^T (natural key order): granule(dcol,key):
//   off(d,key) = tile*4096 + (((d>>4)*2 + (key>>5))*64 + ((key>>3)&3)*16 + (d&15))*8 + (key&7)

// ------------------------------------------------------------------
// m97-style GEMM: A bf16 [M][K], Bt bf16 [N][K]; BK=64, tile BM x 128,
// global_load_lds staging with XOR-swizzled granules.
// ------------------------------------------------------------------
template<int BM>
__global__ __launch_bounds__(256) void gemm_fast(
    const bf16_t* __restrict__ A, const bf16_t* __restrict__ Bt,
    const float* __restrict__ b0, const float* __restrict__ b1,
    const float* __restrict__ b2,
    bf16_t* __restrict__ oq, float* __restrict__ o1, float* __restrict__ o2,
    int M, int K, int N, int mode)
{
    constexpr int MT = BM / 64;
    __shared__ __align__(16) bf16_t As[BM * 64];
    __shared__ __align__(16) bf16_t Bs[128 * 64];

    const int t = threadIdx.x;
    const int wave = t >> 6, lane = t & 63;
    const int quad = lane >> 4, l15 = lane & 15;
    const int rsub = lane >> 3, gq = lane & 7;
    const int m0 = blockIdx.y * BM, n0 = blockIdx.x * 128;

    f32x4 acc[MT][8];
#pragma unroll
    for (int i = 0; i < MT; i++)
#pragma unroll
        for (int j = 0; j < 8; j++) acc[i][j] = (f32x4){0.f, 0.f, 0.f, 0.f};

    for (int k0 = 0; k0 < K; k0 += 64) {
#pragma unroll
        for (int j = 0; j < BM / 32; j++) {
            int row = wave * (BM / 4) + j * 8 + rsub;
            const bf16_t* g = A + (size_t)(m0 + row) * K + k0 + ((gq ^ (row & 7)) * 8);
            dma16(g, As + (wave * (BM / 4) + j * 8) * 64);
        }
#pragma unroll
        for (int j = 0; j < 4; j++) {
            int row = wave * 32 + j * 8 + rsub;
            const bf16_t* g = Bt + (size_t)(n0 + row) * K + k0 + ((gq ^ (row & 7)) * 8);
            dma16(g, Bs + (wave * 32 + j * 8) * 64);
        }
        __syncthreads();

#pragma unroll
        for (int kk = 0; kk < 2; kk++) {
            const int pg = ((kk * 4 + quad) ^ (l15 & 7)) * 8;
            bf16x8 af[MT], bf[8];
#pragma unroll
            for (int mt = 0; mt < MT; mt++)
                af[mt] = *(const bf16x8*)(As + (wave * (BM / 4) + mt * 16 + l15) * 64 + pg);
#pragma unroll
            for (int nt = 0; nt < 8; nt++)
                bf[nt] = *(const bf16x8*)(Bs + (nt * 16 + l15) * 64 + pg);
#pragma unroll
            for (int mt = 0; mt < MT; mt++)
#pragma unroll
                for (int nt = 0; nt < 8; nt++)
                    acc[mt][nt] = mfma16(af[mt], bf[nt], acc[mt][nt]);
        }
        __syncthreads();
    }

#pragma unroll
    for (int mt = 0; mt < MT; mt++)
#pragma unroll
        for (int nt = 0; nt < 8; nt++)
#pragma unroll
            for (int reg = 0; reg < 4; reg++) {
                int m = m0 + wave * (BM / 4) + mt * 16 + quad * 4 + reg;
                int n = n0 + nt * 16 + l15;
                if (mode == 0) {
                    o1[(size_t)m * N + n] = acc[mt][nt][reg] + b0[n];
                } else {
                    int seg = n >> 10, nl = n & 1023;
                    const float* bias = (seg == 0) ? b0 : (seg == 1) ? b1 : b2;
                    float c = acc[mt][nt][reg] + bias[nl];
                    int h = nl >> 6, d = nl & 63;
                    int r = m >> 1, bb = m & 1;
                    size_t off = (((size_t)bb * NH + h) * RLEN + r) * HD + d;
                    if (seg == 0)      oq[off] = (bf16_t)(c * 0.125f);
                    else if (seg == 1) o1[off] = c;
                    else               o2[off] = c;
                }
            }
}

// ------------------------------------------------------------------
// 64x128 MFMA GEMM (small r0 gemm only), padded LDS.
// ------------------------------------------------------------------
__global__ __launch_bounds__(256) void gemm_mfma(
    const bf16_t* __restrict__ A, const bf16_t* __restrict__ Bt,
    const float* __restrict__ bias, float* __restrict__ outf,
    int M, int K, int N, int Rr)
{
    constexpr int LDA = 40;
    __shared__ __align__(16) bf16_t As[64 * LDA];
    __shared__ __align__(16) bf16_t Bs[128 * LDA];

    const int t = threadIdx.x;
    const int wave = t >> 6, lane = t & 63;
    const int quad = lane >> 4, l15 = lane & 15;
    const int wrow = wave >> 1, wcol = wave & 1;
    const int m0 = blockIdx.y * 64, n0 = blockIdx.x * 128;

    f32x4 acc[2][4];
#pragma unroll
    for (int i = 0; i < 2; i++)
#pragma unroll
        for (int j = 0; j < 4; j++) acc[i][j] = (f32x4){0.f, 0.f, 0.f, 0.f};

    const int srow = t >> 2, sseg = (t & 3) * 8;

    for (int k0 = 0; k0 < K; k0 += 32) {
        bf16x8 av  = *(const bf16x8*)(A  + (size_t)(m0 + srow) * K + k0 + sseg);
        bf16x8 bv0 = *(const bf16x8*)(Bt + (size_t)(n0 + srow) * K + k0 + sseg);
        bf16x8 bv1 = *(const bf16x8*)(Bt + (size_t)(n0 + 64 + srow) * K + k0 + sseg);
        __syncthreads();
        *(bf16x8*)(As + srow * LDA + sseg)        = av;
        *(bf16x8*)(Bs + srow * LDA + sseg)        = bv0;
        *(bf16x8*)(Bs + (64 + srow) * LDA + sseg) = bv1;
        __syncthreads();

        bf16x8 af[2], bf[4];
#pragma unroll
        for (int mt = 0; mt < 2; mt++)
            af[mt] = *(const bf16x8*)(As + (wrow * 32 + mt * 16 + l15) * LDA + quad * 8);
#pragma unroll
        for (int nt = 0; nt < 4; nt++)
            bf[nt] = *(const bf16x8*)(Bs + (wcol * 64 + nt * 16 + l15) * LDA + quad * 8);
#pragma unroll
        for (int mt = 0; mt < 2; mt++)
#pragma unroll
            for (int nt = 0; nt < 4; nt++)
                acc[mt][nt] = mfma16(af[mt], bf[nt], acc[mt][nt]);
    }

#pragma unroll
    for (int mt = 0; mt < 2; mt++)
#pragma unroll
        for (int nt = 0; nt < 4; nt++)
#pragma unroll
            for (int reg = 0; reg < 4; reg++) {
                int m = m0 + wrow * 32 + mt * 16 + quad * 4 + reg;
                int n = n0 + wcol * 64 + nt * 16 + l15;
                if (m >= M) continue;
                float c = acc[mt][nt][reg] + bias[n];
                int h = n >> 6, d = n & 63;
                outf[(((size_t)h) * Rr + m) * HD + d] = c;   // [h][z][d]
            }
}

// ------------------------------------------------------------------
// K LayerNorm -> frag-major bf16 (PERMUTED keys). One wave per key row.
// ------------------------------------------------------------------
__global__ __launch_bounds__(256) void ln_k_frag(
    const float* __restrict__ x, const float* __restrict__ g, const float* __restrict__ b,
    bf16_t* __restrict__ kfm)
{
    int row  = blockIdx.x * 4 + (threadIdx.x >> 6);
    int lane = threadIdx.x & 63;
    float v = x[(size_t)row * HD + lane];
    float s1 = v, s2 = v * v;
#pragma unroll
    for (int o = 32; o > 0; o >>= 1) {
        s1 += __shfl_xor(s1, o);
        s2 += __shfl_xor(s2, o);
    }
    float mean = s1 * (1.f / 64.f);
    float var  = s2 * (1.f / 64.f) - mean * mean;
    float y = (v - mean) * rsqrtf(var + 1e-5f) * g[lane] + b[lane];
    int bh = row >> 11, r = row & 2047, d = lane;
    int rt = r & 63;
    size_t off = (size_t)bh * 131072 + (size_t)(r >> 6) * 4096 +
        (size_t)((((rt & 3) * 2 + (d >> 5)) * 64 + ((d >> 3) & 3) * 16 + (rt >> 2)) * 8 + (d & 7));
    kfm[off] = (bf16_t)y;
}

// ------------------------------------------------------------------
// V LayerNorm + transpose -> frag-major bf16 V^T (natural key order).
// ------------------------------------------------------------------
__global__ __launch_bounds__(256) void lnv_frag(
    const float* __restrict__ v, const float* __restrict__ g,
    const float* __restrict__ b, bf16_t* __restrict__ vfm)
{
    __shared__ float tile[64][65];
    const int bh = blockIdx.y, tidx = blockIdx.x;
    const int t = threadIdx.x;
    const int wave = t >> 6, lane = t & 63;

#pragma unroll
    for (int i = 0; i < 16; i++) {
        int rl = wave * 16 + i;
        float x = v[((size_t)bh * RLEN + tidx * 64 + rl) * HD + lane];
        float s1 = x, s2 = x * x;
#pragma unroll
        for (int o = 32; o > 0; o >>= 1) {
            s1 += __shfl_xor(s1, o);
            s2 += __shfl_xor(s2, o);
        }
        float mean = s1 * (1.f / 64.f);
        float var  = s2 * (1.f / 64.f) - mean * mean;
        tile[rl][lane] = (x - mean) * rsqrtf(var + 1e-5f) * g[lane] + b[lane];
    }
    __syncthreads();
    int d = t >> 2, rs = (t & 3) * 16;
    bf16x8 o0, o1;
#pragma unroll
    for (int j = 0; j < 8; j++) {
        o0[j] = (bf16_t)tile[rs + j][d];
        o1[j] = (bf16_t)tile[rs + 8 + j][d];
    }
    size_t base = (size_t)bh * 131072;
    size_t off0 = base + (size_t)((((tidx * 4 + (d >> 4)) * 2 + (rs >> 5)) * 64
                  + ((rs >> 3) & 3) * 16 + (d & 15)) * 8);
    int rs2 = rs + 8;
    size_t off1 = base + (size_t)((((tidx * 4 + (d >> 4)) * 2 + (rs2 >> 5)) * 64
                  + ((rs2 >> 3) & 3) * 16 + (d & 15)) * 8);
    *(bf16x8*)(vfm + off0) = o0;
    *(bf16x8*)(vfm + off1) = o1;
}

// ------------------------------------------------------------------
__global__ __launch_bounds__(256) void cvt_bf16(
    const float* __restrict__ src, bf16_t* __restrict__ dst, int n)
{
    int i = (blockIdx.x * 256 + threadIdx.x) * 4;
    if (i < n) {
        float4 v = *(const float4*)(src + i);
        bf16x4 o;
        o[0] = (bf16_t)v.x; o[1] = (bf16_t)v.y; o[2] = (bf16_t)v.z; o[3] = (bf16_t)v.w;
        *(bf16x4*)(dst + i) = o;
    }
}

// ------------------------------------------------------------------
// Batched weight transpose+cvt -> [n][k] bf16.
// ------------------------------------------------------------------
__global__ __launch_bounds__(256) void wt_batch(
    const float* __restrict__ Wq, const float* __restrict__ Wk,
    const float* __restrict__ Wv, const float* __restrict__ Wo,
    const float* __restrict__ Wr0,
    bf16_t* __restrict__ wqt, bf16_t* __restrict__ wkt,
    bf16_t* __restrict__ wvt, bf16_t* __restrict__ wot,
    bf16_t* __restrict__ wr0t)
{
    __shared__ float tile[64][65];
    const int bid = blockIdx.x;
    const float* src; bf16_t* dst; int R, C, r0, c0;
    if (bid < 1024) {
        int sel = bid >> 8, local = bid & 255;
        src = (sel == 0) ? Wq : (sel == 1) ? Wk : (sel == 2) ? Wv : Wo;
        dst = (sel == 0) ? wqt : (sel == 1) ? wkt : (sel == 2) ? wvt : wot;
        R = ED; C = ED; r0 = (local >> 4) * 64; c0 = (local & 15) * 64;
    } else {
        src = Wr0; dst = wr0t; R = NZ; C = ED; r0 = 0; c0 = (bid - 1024) * 64;
    }
    const int t = threadIdx.x;
#pragma unroll
    for (int i = 0; i < 4; i++) {
        int idx = t + i * 256;
        int r = idx >> 4, c = (idx & 15) * 4;
        float4 vv = *(const float4*)(src + (size_t)(r0 + r) * C + c0 + c);
        tile[r][c] = vv.x; tile[r][c + 1] = vv.y; tile[r][c + 2] = vv.z; tile[r][c + 3] = vv.w;
    }
    __syncthreads();
    int cc = t >> 2, rs = (t & 3) * 16;
    bf16x8 o0, o1;
#pragma unroll
    for (int j = 0; j < 8; j++) {
        o0[j] = (bf16_t)tile[rs + j][cc];
        o1[j] = (bf16_t)tile[rs + 8 + j][cc];
    }
    *(bf16x8*)(dst + (size_t)(c0 + cc) * R + r0 + rs) = o0;
    *(bf16x8*)(dst + (size_t)(c0 + cc) * R + r0 + rs + 8) = o1;
}

// ------------------------------------------------------------------
__global__ __launch_bounds__(256) void sumq_gather(
    const float* __restrict__ emb, const int* __restrict__ ids,
    bf16_t* __restrict__ sum_q)
{
    int sb = blockIdx.x;
    int s = sb >> 1, b = sb & 1;
    int id = ids[b * SLEN + s];
    const float* src = emb + (size_t)id * ED;
    for (int e = threadIdx.x; e < ED; e += 256) {
        int h = e >> 6, d = e & 63;
        sum_q[(((size_t)b * NH + h) * SLEN + s) * HD + d] = (bf16_t)(src[e] * 0.125f);
    }
}

// ------------------------------------------------------------------
// One 64-key attention tile for a wave owning 16 q-rows. Barrier-free:
// global->reg K/V frags (permuted-key K layout), int4 rel loads,
// fp32 qr-table gather, vectorized Ps round-trip.
// ------------------------------------------------------------------
__device__ __forceinline__ void attn_tile(
    const bf16_t* __restrict__ kt, const bf16_t* __restrict__ vt,
    const int* __restrict__ rp0, const int* __restrict__ rp1,
    const int* __restrict__ rp2, const int* __restrict__ rp3,
    bool userel,
    const float* __restrict__ qrsw, bf16_t* __restrict__ Psw,
    bf16x8 qf0, bf16x8 qf1,
    f32x4 (&O)[4], float (&m_i)[4], float (&l_i)[4],
    int quad, int l15, int lane)
{
    bf16x8 kf[4][2];
#pragma unroll
    for (int nt = 0; nt < 4; nt++)
#pragma unroll
        for (int kb = 0; kb < 2; kb++)
            kf[nt][kb] = *(const bf16x8*)(kt + ((nt * 2 + kb) * 64 + lane) * 8);

    int4 crel[4];
    if (userel) {
        crel[0] = *(const int4*)rp0;
        crel[1] = *(const int4*)rp1;
        crel[2] = *(const int4*)rp2;
        crel[3] = *(const int4*)rp3;
    }

    f32x4 S[4];
#pragma unroll
    for (int nt = 0; nt < 4; nt++) {
        f32x4 acc = (f32x4){0.f, 0.f, 0.f, 0.f};
        acc = mfma16(qf0, kf[nt][0], acc);
        acc = mfma16(qf1, kf[nt][1], acc);
        S[nt] = acc;
    }

    // V frags issued now (K regs dead) — latency hides under softmax
    bf16x8 vf[4][2];
#pragma unroll
    for (int nt = 0; nt < 4; nt++)
#pragma unroll
        for (int kb = 0; kb < 2; kb++)
            vf[nt][kb] = *(const bf16x8*)(vt + ((nt * 2 + kb) * 64 + lane) * 8);

    if (userel) {
#pragma unroll
        for (int reg = 0; reg < 4; reg++) {
            const float* qr = qrsw + (quad * 4 + reg) * 64;
            int4 c = crel[reg];
            S[0][reg] += qr[c.x];
            S[1][reg] += qr[c.y];
            S[2][reg] += qr[c.z];
            S[3][reg] += qr[c.w];
        }
    }

    float tmax[4];
#pragma unroll
    for (int reg = 0; reg < 4; reg++) {
        float v = fmaxf(fmaxf(S[0][reg], S[1][reg]), fmaxf(S[2][reg], S[3][reg]));
#pragma unroll
        for (int o = 8; o > 0; o >>= 1) v = fmaxf(v, __shfl_xor(v, o));
        tmax[reg] = v;
    }
    float alpha[4], psum[4];
#pragma unroll
    for (int reg = 0; reg < 4; reg++) {
        float mn = fmaxf(m_i[reg], tmax[reg]);
        alpha[reg] = __expf(m_i[reg] - mn);
        m_i[reg] = mn;
        psum[reg] = 0.f;
    }
#pragma unroll
    for (int nt = 0; nt < 4; nt++)
#pragma unroll
        for (int reg = 0; reg < 4; reg++) {
            float p = __expf(S[nt][reg] - m_i[reg]);
            S[nt][reg] = p;
            psum[reg] += p;
        }
#pragma unroll
    for (int reg = 0; reg < 4; reg++) {
#pragma unroll
        for (int o = 8; o > 0; o >>= 1) psum[reg] += __shfl_xor(psum[reg], o);
        l_i[reg] = l_i[reg] * alpha[reg] + psum[reg];
    }
#pragma unroll
    for (int nt = 0; nt < 4; nt++) {
        O[nt][0] *= alpha[0]; O[nt][1] *= alpha[1];
        O[nt][2] *= alpha[2]; O[nt][3] *= alpha[3];
    }

    // P -> LDS (vectorized: 4 consecutive keys per lane), then PV
#pragma unroll
    for (int reg = 0; reg < 4; reg++) {
        bf16x4 pv;
        pv[0] = (bf16_t)S[0][reg]; pv[1] = (bf16_t)S[1][reg];
        pv[2] = (bf16_t)S[2][reg]; pv[3] = (bf16_t)S[3][reg];
        *(bf16x4*)(Psw + (quad * 4 + reg) * 72 + 4 * l15) = pv;
    }
    bf16x8 pf0 = *(const bf16x8*)(Psw + l15 * 72 + quad * 8);
    bf16x8 pf1 = *(const bf16x8*)(Psw + l15 * 72 + 32 + quad * 8);
#pragma unroll
    for (int nt = 0; nt < 4; nt++) {
        O[nt] = mfma16(pf0, vf[nt][0], O[nt]);
        O[nt] = mfma16(pf1, vf[nt][1], O[nt]);
    }
}

// build fp32 qr table rows quad*4+reg for this wave (16 q-rows)
__device__ __forceinline__ void build_qr(
    const float* __restrict__ r0, int h, bf16x8 qf0, bf16x8 qf1,
    float* __restrict__ qrsw, int quad, int l15)
{
#pragma unroll
    for (int nt = 0; nt < 4; nt++) {
        const float* rp = r0 + ((size_t)h * NZ + l15 + 16 * nt) * HD + quad * 8;
        float4 a0 = *(const float4*)(rp);
        float4 a1 = *(const float4*)(rp + 4);
        bf16x8 bf0;
        bf0[0] = (bf16_t)a0.x; bf0[1] = (bf16_t)a0.y; bf0[2] = (bf16_t)a0.z; bf0[3] = (bf16_t)a0.w;
        bf0[4] = (bf16_t)a1.x; bf0[5] = (bf16_t)a1.y; bf0[6] = (bf16_t)a1.z; bf0[7] = (bf16_t)a1.w;
        float4 b0 = *(const float4*)(rp + 32);
        float4 b1 = *(const float4*)(rp + 36);
        bf16x8 bf1;
        bf1[0] = (bf16_t)b0.x; bf1[1] = (bf16_t)b0.y; bf1[2] = (bf16_t)b0.z; bf1[3] = (bf16_t)b0.w;
        bf1[4] = (bf16_t)b1.x; bf1[5] = (bf16_t)b1.y; bf1[6] = (bf16_t)b1.z; bf1[7] = (bf16_t)b1.w;
        f32x4 qa = (f32x4){0.f, 0.f, 0.f, 0.f};
        qa = mfma16(qf0, bf0, qa);
        qa = mfma16(qf1, bf1, qa);
#pragma unroll
        for (int reg = 0; reg < 4; reg++)
            qrsw[(quad * 4 + reg) * 64 + l15 + 16 * nt] = qa[reg];
    }
}

// ------------------------------------------------------------------
// Summary attention, split-K, barrier-free. grid (32, NSPLIT).
// ------------------------------------------------------------------
__global__ __launch_bounds__(256) void sum_attn_split(
    const bf16_t* __restrict__ Qb,   // sum_q [bh][s][d] row-major
    const bf16_t* __restrict__ kfm, const bf16_t* __restrict__ vfm,
    const float*  __restrict__ r0,
    const int*    __restrict__ rel_idx,
    float* __restrict__ po, float* __restrict__ pm, float* __restrict__ pl)
{
    const int bh = blockIdx.x;
    const int split = blockIdx.y;
    const int b = bh >> 4, h = bh & 15;
    const int t = threadIdx.x;
    const int wave = t >> 6, lane = t & 63;
    const int quad = lane >> 4, l15 = lane & 15;

    __shared__ __align__(16) bf16_t Ps[4][16 * 72];
    __shared__ float qrs[4][16 * 64];

    const bf16_t* Qrow = Qb + ((size_t)bh * SLEN + wave * 16 + l15) * HD;
    bf16x8 qf0 = *(const bf16x8*)(Qrow + quad * 8);
    bf16x8 qf1 = *(const bf16x8*)(Qrow + 32 + quad * 8);

    build_qr(r0, h, qf0, qf1, qrs[wave], quad, l15);

    f32x4 O[4];
    float m_i[4], l_i[4];
#pragma unroll
    for (int nt = 0; nt < 4; nt++) O[nt] = (f32x4){0.f, 0.f, 0.f, 0.f};
#pragma unroll
    for (int r = 0; r < 4; r++) { m_i[r] = -1e30f; l_i[r] = 0.f; }

    const int* relp[4];
#pragma unroll
    for (int reg = 0; reg < 4; reg++)
        relp[reg] = rel_idx + ((size_t)b * KTOT + wave * 16 + quad * 4 + reg) * RLEN + 4 * l15;

    const bf16_t* kbase = kfm + (size_t)bh * 131072 + (size_t)(split * 4) * 4096;
    const bf16_t* vbase = vfm + (size_t)bh * 131072 + (size_t)(split * 4) * 4096;

    for (int i = 0; i < 4; i++) {
        const int koff = (split * 4 + i) * 64;
        attn_tile(kbase + (size_t)i * 4096, vbase + (size_t)i * 4096,
                  relp[0] + koff, relp[1] + koff, relp[2] + koff, relp[3] + koff, true,
                  qrs[wave], Ps[wave], qf0, qf1, O, m_i, l_i, quad, l15, lane);
    }

    const size_t pslot = (size_t)bh * NSPLIT + split;
#pragma unroll
    for (int nt = 0; nt < 4; nt++)
#pragma unroll
        for (int reg = 0; reg < 4; reg++) {
            int sq = wave * 16 + quad * 4 + reg;
            po[(pslot * SLEN + sq) * HD + l15 + 16 * nt] = O[nt][reg];
        }
#pragma unroll
    for (int reg = 0; reg < 4; reg++) {
        int sq = wave * 16 + quad * 4 + reg;
        if (l15 == 0) {
            pm[pslot * SLEN + sq] = m_i[reg];
            pl[pslot * SLEN + sq] = l_i[reg];
        }
    }
}

// ------------------------------------------------------------------
__global__ __launch_bounds__(256) void sum_reduce(
    const float* __restrict__ po, const float* __restrict__ pm,
    const float* __restrict__ pl, float* __restrict__ sum_x2)
{
    const int bh = blockIdx.x;
    const int sg0 = blockIdx.y * 16;
    const int t = threadIdx.x;
    const int d = t & 63, si = t >> 6;
#pragma unroll
    for (int i = 0; i < 4; i++) {
        int s = sg0 + si * 4 + i;
        float M = -1e30f, mm[NSPLIT];
#pragma unroll
        for (int j = 0; j < NSPLIT; j++) {
            mm[j] = pm[((size_t)bh * NSPLIT + j) * SLEN + s];
            M = fmaxf(M, mm[j]);
        }
        float L = 0.f, acc = 0.f;
#pragma unroll
        for (int j = 0; j < NSPLIT; j++) {
            float a = __expf(mm[j] - M);
            L += pl[((size_t)bh * NSPLIT + j) * SLEN + s] * a;
            acc += po[(((size_t)bh * NSPLIT + j) * SLEN + s) * HD + d] * a;
        }
        sum_x2[((size_t)bh * SLEN + s) * HD + d] = acc / L;
    }
}

// ------------------------------------------------------------------
// sum_k2 / sum_v2: y = LN(x @ W + b); frag-major bf16 single tile.
// K2 uses PERMUTED key layout; V2^T natural.
// ------------------------------------------------------------------
__global__ __launch_bounds__(64) void k2v2(
    const float* __restrict__ sum_x2,
    const float* __restrict__ Wk2, const float* __restrict__ bk2,
    const float* __restrict__ Wv2, const float* __restrict__ bv2,
    const float* __restrict__ gk, const float* __restrict__ bk,
    const float* __restrict__ gv, const float* __restrict__ bv,
    bf16_t* __restrict__ k2fm, bf16_t* __restrict__ v2fm)
{
    int row = blockIdx.x;              // bh*64 + s
    int d = threadIdx.x;
    int bh = row >> 6, s = row & 63;
    __shared__ float xs[64];
    xs[d] = sum_x2[(size_t)row * HD + d];
    __syncthreads();

#pragma unroll
    for (int which = 0; which < 2; which++) {
        const float* W  = which ? Wv2 : Wk2;
        const float* bi = which ? bv2 : bk2;
        const float* g  = which ? gv : gk;
        const float* bb = which ? bv : bk;
        float a = bi[d];
#pragma unroll
        for (int j = 0; j < 64; j++) a += xs[j] * W[j * HD + d];
        float s1 = a, s2 = a * a;
#pragma unroll
        for (int o = 32; o > 0; o >>= 1) {
            s1 += __shfl_xor(s1, o);
            s2 += __shfl_xor(s2, o);
        }
        float mean = s1 * (1.f / 64.f);
        float var  = s2 * (1.f / 64.f) - mean * mean;
        float y = (a - mean) * rsqrtf(var + 1e-5f) * g[d] + bb[d];
        if (which == 0) {
            size_t off = (size_t)bh * 4096 +
                (size_t)((((s & 3) * 2 + (d >> 5)) * 64
                          + ((d >> 3) & 3) * 16 + (s >> 2)) * 8 + (d & 7));
            k2fm[off] = (bf16_t)y;
        } else {
            size_t off = (size_t)bh * 4096 +
                (size_t)((((d >> 4) * 2 + (s >> 5)) * 64
                          + ((s >> 3) & 3) * 16 + (d & 15)) * 8 + (s & 7));
            v2fm[off] = (bf16_t)y;
        }
    }
}

// ------------------------------------------------------------------
// Main attention, barrier-free MFMA flash. Each wave owns 16 q-rows,
// streams all 33 key-tiles global->reg. grid 1024 (4 blocks/CU).
// ------------------------------------------------------------------
__global__ __launch_bounds__(256) void reg_attn_mfma(
    const bf16_t* __restrict__ Qb,    // [bh][r][d] row-major
    const bf16_t* __restrict__ kfm, const bf16_t* __restrict__ vfm,
    const bf16_t* __restrict__ k2fm, const bf16_t* __restrict__ v2fm,
    const float*  __restrict__ r0,
    const int*    __restrict__ rel_idx,
    bf16_t* __restrict__ attn_out)    // [r][b][E] bf16
{
    const int bid = blockIdx.x;       // 1024 = 8 XCD x 4 bh x 32 qtiles
    const int bh = (bid & 7) * 4 + ((bid >> 3) & 3);
    const int qt = bid >> 5;          // 0..31
    const int b = bh >> 4, h = bh & 15;
    const int q0 = qt * 64;

    const int t = threadIdx.x;
    const int wave = t >> 6, lane = t & 63;
    const int quad = lane >> 4, l15 = lane & 15;

    __shared__ __align__(16) bf16_t Ps[4][16 * 72];
    __shared__ float qrs[4][16 * 64];

    const bf16_t* Qrow = Qb + ((size_t)bh * RLEN + q0 + wave * 16 + l15) * HD;
    bf16x8 qf0 = *(const bf16x8*)(Qrow + quad * 8);
    bf16x8 qf1 = *(const bf16x8*)(Qrow + 32 + quad * 8);

    build_qr(r0, h, qf0, qf1, qrs[wave], quad, l15);

    f32x4 O[4];
    float m_i[4], l_i[4];
#pragma unroll
    for (int nt = 0; nt < 4; nt++) O[nt] = (f32x4){0.f, 0.f, 0.f, 0.f};
#pragma unroll
    for (int r = 0; r < 4; r++) { m_i[r] = -1e30f; l_i[r] = 0.f; }

    const int* relp[4];
#pragma unroll
    for (int reg = 0; reg < 4; reg++)
        relp[reg] = rel_idx +
            ((size_t)b * KTOT + SLEN + q0 + wave * 16 + quad * 4 + reg) * RLEN + 4 * l15;

    // summary tile (no rel bias), peeled
    attn_tile(k2fm + (size_t)bh * 4096, v2fm + (size_t)bh * 4096,
              nullptr, nullptr, nullptr, nullptr, false,
              qrs[wave], Ps[wave], qf0, qf1, O, m_i, l_i, quad, l15, lane);

    const bf16_t* kt = kfm + (size_t)bh * 131072;
    const bf16_t* vt = vfm + (size_t)bh * 131072;
    for (int tile = 0; tile < 32; tile++) {
        const int koff = tile * 64;
        attn_tile(kt, vt,
                  relp[0] + koff, relp[1] + koff, relp[2] + koff, relp[3] + koff, true,
                  qrs[wave], Ps[wave], qf0, qf1, O, m_i, l_i, quad, l15, lane);
        kt += 4096; vt += 4096;
    }

    float linv[4];
#pragma unroll
    for (int reg = 0; reg < 4; reg++) linv[reg] = 1.0f / l_i[reg];
#pragma unroll
    for (int nt = 0; nt < 4; nt++)
#pragma unroll
        for (int reg = 0; reg < 4; reg++) {
            int q = q0 + wave * 16 + quad * 4 + reg;
            attn_out[((size_t)q * BSZ + b) * ED + h * HD + l15 + 16 * nt] =
                (bf16_t)(O[nt][reg] * linv[reg]);
        }
}

// ------------------------------------------------------------------
extern "C" void kernel_launch(void* const* d_in, const int* in_sizes, int n_in,
                              void* d_out, int out_size, void* d_ws, size_t ws_size,
                              hipStream_t stream)
{
    const float* reg_x    = (const float*)d_in[0];
    const int*   sum_ids  = (const int*)d_in[1];
    const int*   rel_idx  = (const int*)d_in[2];
    const float* emb_sum  = (const float*)d_in[5];
    const float* rel_emb0 = (const float*)d_in[6];
    const float* Wq = (const float*)d_in[7];
    const float* bq = (const float*)d_in[8];
    const float* Wk = (const float*)d_in[9];
    const float* bk = (const float*)d_in[10];
    const float* Wv = (const float*)d_in[11];
    const float* bv = (const float*)d_in[12];
    const float* Wr0 = (const float*)d_in[13];
    const float* br0 = (const float*)d_in[14];
    const float* Wk2 = (const float*)d_in[15];
    const float* bk2 = (const float*)d_in[16];
    const float* Wv2 = (const float*)d_in[17];
    const float* bv2 = (const float*)d_in[18];
    const float* Wo  = (const float*)d_in[19];
    const float* bo  = (const float*)d_in[20];
    const float* ln_k_g  = (const float*)d_in[21];
    const float* ln_k_b  = (const float*)d_in[22];
    const float* ln_v_g  = (const float*)d_in[23];
    const float* ln_v_b  = (const float*)d_in[24];
    const float* ln_k2_g = (const float*)d_in[25];
    const float* ln_k2_b = (const float*)d_in[26];
    const float* ln_v2_g = (const float*)d_in[27];
    const float* ln_v2_b = (const float*)d_in[28];

    const size_t QKV = (size_t)BSZ * NH * RLEN * HD;   // 4,194,304
    const size_t SUM = (size_t)BSZ * NH * SLEN * HD;   // 131,072

    float* ws  = (float*)d_ws;
    float* k   = ws;                    // fp32 K; later aliased by aob
    float* v   = k + QKV;               // fp32 V
    float* r0  = v + QKV;
    float* sx2 = r0 + (size_t)NH * NZ * HD;

    bf16_t* xb   = (bf16_t*)(sx2 + SUM);   // dead after QKV gemm -> po
    bf16_t* qb   = xb + QKV;
    bf16_t* kfm  = qb + QKV;
    bf16_t* vfm  = kfm + QKV;
    bf16_t* sqb  = vfm + QKV;
    bf16_t* k2fm = sqb + SUM;
    bf16_t* v2fm = k2fm + SUM;
    bf16_t* wqt  = v2fm + SUM;          // wqt|wkt|wvt contiguous [3072][1024]
    bf16_t* wkt  = wqt + (size_t)ED * ED;
    bf16_t* wvt  = wkt + (size_t)ED * ED;
    bf16_t* wot  = wvt + (size_t)ED * ED;
    bf16_t* wr0t = wot + (size_t)ED * ED;
    bf16_t* re0b = wr0t + (size_t)ED * NZ;
    bf16_t* aob  = (bf16_t*)k;
    float*  po   = (float*)xb;
    float*  pm   = po + (size_t)BSZ * NH * NSPLIT * SLEN * HD;
    float*  pl   = pm + (size_t)BSZ * NH * NSPLIT * SLEN;

    const int M = RLEN * BSZ;   // 4096

    cvt_bf16<<<(int)(QKV / 1024), 256, 0, stream>>>(reg_x, xb, (int)QKV);
    cvt_bf16<<<4, 256, 0, stream>>>(rel_emb0, re0b, NZ * NZ);
    wt_batch<<<1040, 256, 0, stream>>>(Wq, Wk, Wv, Wo, Wr0, wqt, wkt, wvt, wot, wr0t);

    gemm_fast<128><<<dim3(3 * ED / 128, M / 128), 256, 0, stream>>>(
        xb, wqt, bq, bk, bv, qb, k, v, M, ED, 3 * ED, 1);

    ln_k_frag<<<(BSZ * NH * RLEN) / 4, 256, 0, stream>>>(k, ln_k_g, ln_k_b, kfm);
    lnv_frag<<<dim3(RLEN / 64, BSZ * NH), 256, 0, stream>>>(v, ln_v_g, ln_v_b, vfm);

    gemm_mfma<<<dim3(ED / 128, 1), 256, 0, stream>>>(re0b, wr0t, br0, r0, NZ, NZ, ED, NZ);

    sumq_gather<<<SLEN * BSZ, 256, 0, stream>>>(emb_sum, sum_ids, sqb);

    sum_attn_split<<<dim3(BSZ * NH, NSPLIT), 256, 0, stream>>>(sqb, kfm, vfm, r0, rel_idx, po, pm, pl);
    sum_reduce<<<dim3(BSZ * NH, 4), 256, 0, stream>>>(po, pm, pl, sx2);

    k2v2<<<BSZ * NH * SLEN, 64, 0, stream>>>(sx2, Wk2, bk2, Wv2, bv2,
                                             ln_k2_g, ln_k2_b, ln_v2_g, ln_v2_b, k2fm, v2fm);

    reg_attn_mfma<<<1024, 256, 0, stream>>>(qb, kfm, vfm, k2fm, v2fm, r0, rel_idx, aob);

    gemm_fast<64><<<dim3(ED / 128, M / 64), 256, 0, stream>>>(
        aob, wot, bo, nullptr, nullptr, nullptr, (float*)d_out, nullptr, M, ED, ED, 0);
}

// Round 8
// 366.446 us; speedup vs baseline: 1.2523x; 1.1395x over previous
//
#include <hip/hip_runtime.h>
#include <cstdint>
#include <cstddef>

#define NH   16
#define HD   64
#define RLEN 2048
#define BSZ  2
#define SLEN 64
#define NZ   64
#define ED   1024
#define KTOT 2112   // SLEN + RLEN
#define NSPLIT 8    // sum_attn key splits

typedef __bf16 bf16_t;
typedef bf16_t bf16x8 __attribute__((ext_vector_type(8)));
typedef bf16_t bf16x4 __attribute__((ext_vector_type(4)));
typedef float  f32x4  __attribute__((ext_vector_type(4)));

__device__ __forceinline__ f32x4 mfma16(bf16x8 a, bf16x8 b, f32x4 c) {
    return __builtin_amdgcn_mfma_f32_16x16x32_bf16(a, b, c, 0, 0, 0);
}

// async global->LDS DMA, 16B per lane (used by gemm_fast only)
__device__ __forceinline__ void dma16(const void* g, void* l) {
    __builtin_amdgcn_global_load_lds(
        (const __attribute__((address_space(1))) unsigned int*)g,
        (__attribute__((address_space(3))) unsigned int*)l, 16, 0, 0);
}

// Frag-major K layout per bh (PERMUTED keys: within a 64-key tile, MFMA
// group nt holds keys {4*l15+nt}):
//   off(key,d) = tile*4096 + (((key&3)*2 + (d>>5))*64 + ((d>>3)&3)*16 + ((key>>2)&15))*8 + (d&7)
// Frag-major V^T (natural key order): granule(dcol,key):
//   off(d,key) = tile*4096 + (((d>>4)*2 + (key>>5))*64 + ((key>>3)&3)*16 + (d&15))*8 + (key&7)

// ------------------------------------------------------------------
// m97-style GEMM: A bf16 [M][K], Bt bf16 [N][K]; BK=64, tile BM x 128,
// global_load_lds staging with XOR-swizzled granules.
// ------------------------------------------------------------------
template<int BM>
__global__ __launch_bounds__(256) void gemm_fast(
    const bf16_t* __restrict__ A, const bf16_t* __restrict__ Bt,
    const float* __restrict__ b0, const float* __restrict__ b1,
    const float* __restrict__ b2,
    bf16_t* __restrict__ oq, float* __restrict__ o1, float* __restrict__ o2,
    int M, int K, int N, int mode)
{
    constexpr int MT = BM / 64;
    __shared__ __align__(16) bf16_t As[BM * 64];
    __shared__ __align__(16) bf16_t Bs[128 * 64];

    const int t = threadIdx.x;
    const int wave = t >> 6, lane = t & 63;
    const int quad = lane >> 4, l15 = lane & 15;
    const int rsub = lane >> 3, gq = lane & 7;
    const int m0 = blockIdx.y * BM, n0 = blockIdx.x * 128;

    f32x4 acc[MT][8];
#pragma unroll
    for (int i = 0; i < MT; i++)
#pragma unroll
        for (int j = 0; j < 8; j++) acc[i][j] = (f32x4){0.f, 0.f, 0.f, 0.f};

    for (int k0 = 0; k0 < K; k0 += 64) {
#pragma unroll
        for (int j = 0; j < BM / 32; j++) {
            int row = wave * (BM / 4) + j * 8 + rsub;
            const bf16_t* g = A + (size_t)(m0 + row) * K + k0 + ((gq ^ (row & 7)) * 8);
            dma16(g, As + (wave * (BM / 4) + j * 8) * 64);
        }
#pragma unroll
        for (int j = 0; j < 4; j++) {
            int row = wave * 32 + j * 8 + rsub;
            const bf16_t* g = Bt + (size_t)(n0 + row) * K + k0 + ((gq ^ (row & 7)) * 8);
            dma16(g, Bs + (wave * 32 + j * 8) * 64);
        }
        __syncthreads();

#pragma unroll
        for (int kk = 0; kk < 2; kk++) {
            const int pg = ((kk * 4 + quad) ^ (l15 & 7)) * 8;
            bf16x8 af[MT], bf[8];
#pragma unroll
            for (int mt = 0; mt < MT; mt++)
                af[mt] = *(const bf16x8*)(As + (wave * (BM / 4) + mt * 16 + l15) * 64 + pg);
#pragma unroll
            for (int nt = 0; nt < 8; nt++)
                bf[nt] = *(const bf16x8*)(Bs + (nt * 16 + l15) * 64 + pg);
#pragma unroll
            for (int mt = 0; mt < MT; mt++)
#pragma unroll
                for (int nt = 0; nt < 8; nt++)
                    acc[mt][nt] = mfma16(af[mt], bf[nt], acc[mt][nt]);
        }
        __syncthreads();
    }

#pragma unroll
    for (int mt = 0; mt < MT; mt++)
#pragma unroll
        for (int nt = 0; nt < 8; nt++)
#pragma unroll
            for (int reg = 0; reg < 4; reg++) {
                int m = m0 + wave * (BM / 4) + mt * 16 + quad * 4 + reg;
                int n = n0 + nt * 16 + l15;
                if (mode == 0) {
                    o1[(size_t)m * N + n] = acc[mt][nt][reg] + b0[n];
                } else {
                    int seg = n >> 10, nl = n & 1023;
                    const float* bias = (seg == 0) ? b0 : (seg == 1) ? b1 : b2;
                    float c = acc[mt][nt][reg] + bias[nl];
                    int h = nl >> 6, d = nl & 63;
                    int r = m >> 1, bb = m & 1;
                    size_t off = (((size_t)bb * NH + h) * RLEN + r) * HD + d;
                    if (seg == 0)      oq[off] = (bf16_t)(c * 0.125f);
                    else if (seg == 1) o1[off] = c;
                    else               o2[off] = c;
                }
            }
}

// ------------------------------------------------------------------
// 64x128 MFMA GEMM (small r0 gemm only), padded LDS.
// ------------------------------------------------------------------
__global__ __launch_bounds__(256) void gemm_mfma(
    const bf16_t* __restrict__ A, const bf16_t* __restrict__ Bt,
    const float* __restrict__ bias, float* __restrict__ outf,
    int M, int K, int N, int Rr)
{
    constexpr int LDA = 40;
    __shared__ __align__(16) bf16_t As[64 * LDA];
    __shared__ __align__(16) bf16_t Bs[128 * LDA];

    const int t = threadIdx.x;
    const int wave = t >> 6, lane = t & 63;
    const int quad = lane >> 4, l15 = lane & 15;
    const int wrow = wave >> 1, wcol = wave & 1;
    const int m0 = blockIdx.y * 64, n0 = blockIdx.x * 128;

    f32x4 acc[2][4];
#pragma unroll
    for (int i = 0; i < 2; i++)
#pragma unroll
        for (int j = 0; j < 4; j++) acc[i][j] = (f32x4){0.f, 0.f, 0.f, 0.f};

    const int srow = t >> 2, sseg = (t & 3) * 8;

    for (int k0 = 0; k0 < K; k0 += 32) {
        bf16x8 av  = *(const bf16x8*)(A  + (size_t)(m0 + srow) * K + k0 + sseg);
        bf16x8 bv0 = *(const bf16x8*)(Bt + (size_t)(n0 + srow) * K + k0 + sseg);
        bf16x8 bv1 = *(const bf16x8*)(Bt + (size_t)(n0 + 64 + srow) * K + k0 + sseg);
        __syncthreads();
        *(bf16x8*)(As + srow * LDA + sseg)        = av;
        *(bf16x8*)(Bs + srow * LDA + sseg)        = bv0;
        *(bf16x8*)(Bs + (64 + srow) * LDA + sseg) = bv1;
        __syncthreads();

        bf16x8 af[2], bf[4];
#pragma unroll
        for (int mt = 0; mt < 2; mt++)
            af[mt] = *(const bf16x8*)(As + (wrow * 32 + mt * 16 + l15) * LDA + quad * 8);
#pragma unroll
        for (int nt = 0; nt < 4; nt++)
            bf[nt] = *(const bf16x8*)(Bs + (wcol * 64 + nt * 16 + l15) * LDA + quad * 8);
#pragma unroll
        for (int mt = 0; mt < 2; mt++)
#pragma unroll
            for (int nt = 0; nt < 4; nt++)
                acc[mt][nt] = mfma16(af[mt], bf[nt], acc[mt][nt]);
    }

#pragma unroll
    for (int mt = 0; mt < 2; mt++)
#pragma unroll
        for (int nt = 0; nt < 4; nt++)
#pragma unroll
            for (int reg = 0; reg < 4; reg++) {
                int m = m0 + wrow * 32 + mt * 16 + quad * 4 + reg;
                int n = n0 + wcol * 64 + nt * 16 + l15;
                if (m >= M) continue;
                float c = acc[mt][nt][reg] + bias[n];
                int h = n >> 6, d = n & 63;
                outf[(((size_t)h) * Rr + m) * HD + d] = c;   // [h][z][d]
            }
}

// ------------------------------------------------------------------
// K LayerNorm -> frag-major bf16 (PERMUTED keys). One wave per key row.
// ------------------------------------------------------------------
__global__ __launch_bounds__(256) void ln_k_frag(
    const float* __restrict__ x, const float* __restrict__ g, const float* __restrict__ b,
    bf16_t* __restrict__ kfm)
{
    int row  = blockIdx.x * 4 + (threadIdx.x >> 6);
    int lane = threadIdx.x & 63;
    float v = x[(size_t)row * HD + lane];
    float s1 = v, s2 = v * v;
#pragma unroll
    for (int o = 32; o > 0; o >>= 1) {
        s1 += __shfl_xor(s1, o);
        s2 += __shfl_xor(s2, o);
    }
    float mean = s1 * (1.f / 64.f);
    float var  = s2 * (1.f / 64.f) - mean * mean;
    float y = (v - mean) * rsqrtf(var + 1e-5f) * g[lane] + b[lane];
    int bh = row >> 11, r = row & 2047, d = lane;
    int rt = r & 63;
    size_t off = (size_t)bh * 131072 + (size_t)(r >> 6) * 4096 +
        (size_t)((((rt & 3) * 2 + (d >> 5)) * 64 + ((d >> 3) & 3) * 16 + (rt >> 2)) * 8 + (d & 7));
    kfm[off] = (bf16_t)y;
}

// ------------------------------------------------------------------
// V LayerNorm + transpose -> frag-major bf16 V^T (natural key order).
// ------------------------------------------------------------------
__global__ __launch_bounds__(256) void lnv_frag(
    const float* __restrict__ v, const float* __restrict__ g,
    const float* __restrict__ b, bf16_t* __restrict__ vfm)
{
    __shared__ float tile[64][65];
    const int bh = blockIdx.y, tidx = blockIdx.x;
    const int t = threadIdx.x;
    const int wave = t >> 6, lane = t & 63;

#pragma unroll
    for (int i = 0; i < 16; i++) {
        int rl = wave * 16 + i;
        float x = v[((size_t)bh * RLEN + tidx * 64 + rl) * HD + lane];
        float s1 = x, s2 = x * x;
#pragma unroll
        for (int o = 32; o > 0; o >>= 1) {
            s1 += __shfl_xor(s1, o);
            s2 += __shfl_xor(s2, o);
        }
        float mean = s1 * (1.f / 64.f);
        float var  = s2 * (1.f / 64.f) - mean * mean;
        tile[rl][lane] = (x - mean) * rsqrtf(var + 1e-5f) * g[lane] + b[lane];
    }
    __syncthreads();
    int d = t >> 2, rs = (t & 3) * 16;
    bf16x8 o0, o1;
#pragma unroll
    for (int j = 0; j < 8; j++) {
        o0[j] = (bf16_t)tile[rs + j][d];
        o1[j] = (bf16_t)tile[rs + 8 + j][d];
    }
    size_t base = (size_t)bh * 131072;
    size_t off0 = base + (size_t)((((tidx * 4 + (d >> 4)) * 2 + (rs >> 5)) * 64
                  + ((rs >> 3) & 3) * 16 + (d & 15)) * 8);
    int rs2 = rs + 8;
    size_t off1 = base + (size_t)((((tidx * 4 + (d >> 4)) * 2 + (rs2 >> 5)) * 64
                  + ((rs2 >> 3) & 3) * 16 + (d & 15)) * 8);
    *(bf16x8*)(vfm + off0) = o0;
    *(bf16x8*)(vfm + off1) = o1;
}

// ------------------------------------------------------------------
__global__ __launch_bounds__(256) void cvt_bf16(
    const float* __restrict__ src, bf16_t* __restrict__ dst, int n)
{
    int i = (blockIdx.x * 256 + threadIdx.x) * 4;
    if (i < n) {
        float4 v = *(const float4*)(src + i);
        bf16x4 o;
        o[0] = (bf16_t)v.x; o[1] = (bf16_t)v.y; o[2] = (bf16_t)v.z; o[3] = (bf16_t)v.w;
        *(bf16x4*)(dst + i) = o;
    }
}

// ------------------------------------------------------------------
// Prep kernel: batched weight transpose+cvt (bids 0..1039), sum_q
// gather (1040..1167), rel_emb0 cvt (1168..1171).
// ------------------------------------------------------------------
__global__ __launch_bounds__(256) void prep_batch(
    const float* __restrict__ Wq, const float* __restrict__ Wk,
    const float* __restrict__ Wv, const float* __restrict__ Wo,
    const float* __restrict__ Wr0,
    bf16_t* __restrict__ wqt, bf16_t* __restrict__ wkt,
    bf16_t* __restrict__ wvt, bf16_t* __restrict__ wot,
    bf16_t* __restrict__ wr0t,
    const float* __restrict__ emb, const int* __restrict__ ids,
    bf16_t* __restrict__ sum_q,
    const float* __restrict__ rel_emb0, bf16_t* __restrict__ re0b)
{
    const int bid = blockIdx.x;
    const int t = threadIdx.x;

    if (bid >= 1168) {          // rel_emb0 cvt (4096 elems)
        int i = ((bid - 1168) * 256 + t) * 4;
        float4 v = *(const float4*)(rel_emb0 + i);
        bf16x4 o;
        o[0] = (bf16_t)v.x; o[1] = (bf16_t)v.y; o[2] = (bf16_t)v.z; o[3] = (bf16_t)v.w;
        *(bf16x4*)(re0b + i) = o;
        return;
    }
    if (bid >= 1040) {          // sum_q gather
        int sb = bid - 1040;
        int s = sb >> 1, b = sb & 1;
        int id = ids[b * SLEN + s];
        const float* src = emb + (size_t)id * ED;
        for (int e = t; e < ED; e += 256) {
            int h = e >> 6, d = e & 63;
            sum_q[(((size_t)b * NH + h) * SLEN + s) * HD + d] = (bf16_t)(src[e] * 0.125f);
        }
        return;
    }

    __shared__ float tile[64][65];
    const float* src; bf16_t* dst; int R, C, r0, c0;
    if (bid < 1024) {
        int sel = bid >> 8, local = bid & 255;
        src = (sel == 0) ? Wq : (sel == 1) ? Wk : (sel == 2) ? Wv : Wo;
        dst = (sel == 0) ? wqt : (sel == 1) ? wkt : (sel == 2) ? wvt : wot;
        R = ED; C = ED; r0 = (local >> 4) * 64; c0 = (local & 15) * 64;
    } else {
        src = Wr0; dst = wr0t; R = NZ; C = ED; r0 = 0; c0 = (bid - 1024) * 64;
    }
#pragma unroll
    for (int i = 0; i < 4; i++) {
        int idx = t + i * 256;
        int r = idx >> 4, c = (idx & 15) * 4;
        float4 vv = *(const float4*)(src + (size_t)(r0 + r) * C + c0 + c);
        tile[r][c] = vv.x; tile[r][c + 1] = vv.y; tile[r][c + 2] = vv.z; tile[r][c + 3] = vv.w;
    }
    __syncthreads();
    int cc = t >> 2, rs = (t & 3) * 16;
    bf16x8 o0, o1;
#pragma unroll
    for (int j = 0; j < 8; j++) {
        o0[j] = (bf16_t)tile[rs + j][cc];
        o1[j] = (bf16_t)tile[rs + 8 + j][cc];
    }
    *(bf16x8*)(dst + (size_t)(c0 + cc) * R + r0 + rs) = o0;
    *(bf16x8*)(dst + (size_t)(c0 + cc) * R + r0 + rs + 8) = o1;
}

// ------------------------------------------------------------------
// One 64-key attention tile for a wave owning MT*16 q-rows.
// Barrier-free. Softmax: shared quad-group max (one 4-shfl chain),
// row sums via MFMA with all-ones B operand.
// ------------------------------------------------------------------
template<int MT>
__device__ __forceinline__ void attn_tile(
    const bf16_t* __restrict__ kt, const bf16_t* __restrict__ vt,
    const int* __restrict__ relbase, int koff, bool userel,
    const float* __restrict__ qrsw, bf16_t* __restrict__ Psw,
    const bf16x8 (&qf)[MT][2],
    f32x4 (&O)[MT][4], float& m_q, float (&l_i)[MT][4],
    int quad, int l15, int lane)
{
    bf16x8 kf[4][2];
#pragma unroll
    for (int nt = 0; nt < 4; nt++)
#pragma unroll
        for (int kb = 0; kb < 2; kb++)
            kf[nt][kb] = *(const bf16x8*)(kt + ((nt * 2 + kb) * 64 + lane) * 8);

    int4 crel[MT][4];
    if (userel) {
#pragma unroll
        for (int mt = 0; mt < MT; mt++)
#pragma unroll
            for (int reg = 0; reg < 4; reg++)
                crel[mt][reg] = *(const int4*)(relbase + (size_t)(mt * 16 + reg) * RLEN + koff);
    }

    f32x4 S[MT][4];
#pragma unroll
    for (int mt = 0; mt < MT; mt++)
#pragma unroll
        for (int nt = 0; nt < 4; nt++) {
            f32x4 acc = (f32x4){0.f, 0.f, 0.f, 0.f};
            acc = mfma16(qf[mt][0], kf[nt][0], acc);
            acc = mfma16(qf[mt][1], kf[nt][1], acc);
            S[mt][nt] = acc;
        }

    // V frags issued now (K regs dead) — latency hides under softmax
    bf16x8 vf[4][2];
#pragma unroll
    for (int nt = 0; nt < 4; nt++)
#pragma unroll
        for (int kb = 0; kb < 2; kb++)
            vf[nt][kb] = *(const bf16x8*)(vt + ((nt * 2 + kb) * 64 + lane) * 8);

    if (userel) {
#pragma unroll
        for (int mt = 0; mt < MT; mt++)
#pragma unroll
            for (int reg = 0; reg < 4; reg++) {
                const float* qr = qrsw + (mt * 16 + quad * 4 + reg) * 64;
                int4 c = crel[mt][reg];
                S[mt][0][reg] += qr[c.x];
                S[mt][1][reg] += qr[c.y];
                S[mt][2][reg] += qr[c.z];
                S[mt][3][reg] += qr[c.w];
            }
    }

    // shared quad-group max: one shuffle chain for all MT*4 rows
    float v = -1e30f;
#pragma unroll
    for (int mt = 0; mt < MT; mt++)
#pragma unroll
        for (int nt = 0; nt < 4; nt++) {
            f32x4 s = S[mt][nt];
            v = fmaxf(v, fmaxf(fmaxf(s[0], s[1]), fmaxf(s[2], s[3])));
        }
#pragma unroll
    for (int o = 8; o > 0; o >>= 1) v = fmaxf(v, __shfl_xor(v, o));
    float mnew = fmaxf(m_q, v);
    float alpha = __expf(m_q - mnew);
    m_q = mnew;

#pragma unroll
    for (int mt = 0; mt < MT; mt++)
#pragma unroll
        for (int nt = 0; nt < 4; nt++)
#pragma unroll
            for (int reg = 0; reg < 4; reg++)
                S[mt][nt][reg] = __expf(S[mt][nt][reg] - mnew);

#pragma unroll
    for (int mt = 0; mt < MT; mt++) {
#pragma unroll
        for (int nt = 0; nt < 4; nt++) {
            O[mt][nt][0] *= alpha; O[mt][nt][1] *= alpha;
            O[mt][nt][2] *= alpha; O[mt][nt][3] *= alpha;
        }
#pragma unroll
        for (int reg = 0; reg < 4; reg++) l_i[mt][reg] *= alpha;
    }

    // P -> LDS (4 consecutive keys per lane), PV + row-sum via MFMA-ones
    bf16x8 ones;
#pragma unroll
    for (int j = 0; j < 8; j++) ones[j] = (bf16_t)1.0f;

#pragma unroll
    for (int mt = 0; mt < MT; mt++)
#pragma unroll
        for (int reg = 0; reg < 4; reg++) {
            bf16x4 pv;
            pv[0] = (bf16_t)S[mt][0][reg]; pv[1] = (bf16_t)S[mt][1][reg];
            pv[2] = (bf16_t)S[mt][2][reg]; pv[3] = (bf16_t)S[mt][3][reg];
            *(bf16x4*)(Psw + (mt * 16 + quad * 4 + reg) * 72 + 4 * l15) = pv;
        }

#pragma unroll
    for (int mt = 0; mt < MT; mt++) {
        bf16x8 pf0 = *(const bf16x8*)(Psw + (mt * 16 + l15) * 72 + quad * 8);
        bf16x8 pf1 = *(const bf16x8*)(Psw + (mt * 16 + l15) * 72 + 32 + quad * 8);
        f32x4 ls = (f32x4){0.f, 0.f, 0.f, 0.f};
        ls = mfma16(pf0, ones, ls);
        ls = mfma16(pf1, ones, ls);
#pragma unroll
        for (int nt = 0; nt < 4; nt++) {
            O[mt][nt] = mfma16(pf0, vf[nt][0], O[mt][nt]);
            O[mt][nt] = mfma16(pf1, vf[nt][1], O[mt][nt]);
        }
#pragma unroll
        for (int reg = 0; reg < 4; reg++) l_i[mt][reg] += ls[reg];
    }
}

// build fp32 qr table rows (mt*16 + quad*4 + reg) for this wave
template<int MT>
__device__ __forceinline__ void build_qr(
    const float* __restrict__ r0, int h, const bf16x8 (&qf)[MT][2],
    float* __restrict__ qrsw, int quad, int l15)
{
#pragma unroll
    for (int nt = 0; nt < 4; nt++) {
        const float* rp = r0 + ((size_t)h * NZ + l15 + 16 * nt) * HD + quad * 8;
        float4 a0 = *(const float4*)(rp);
        float4 a1 = *(const float4*)(rp + 4);
        bf16x8 bf0;
        bf0[0] = (bf16_t)a0.x; bf0[1] = (bf16_t)a0.y; bf0[2] = (bf16_t)a0.z; bf0[3] = (bf16_t)a0.w;
        bf0[4] = (bf16_t)a1.x; bf0[5] = (bf16_t)a1.y; bf0[6] = (bf16_t)a1.z; bf0[7] = (bf16_t)a1.w;
        float4 b0 = *(const float4*)(rp + 32);
        float4 b1 = *(const float4*)(rp + 36);
        bf16x8 bf1;
        bf1[0] = (bf16_t)b0.x; bf1[1] = (bf16_t)b0.y; bf1[2] = (bf16_t)b0.z; bf1[3] = (bf16_t)b0.w;
        bf1[4] = (bf16_t)b1.x; bf1[5] = (bf16_t)b1.y; bf1[6] = (bf16_t)b1.z; bf1[7] = (bf16_t)b1.w;
#pragma unroll
        for (int mt = 0; mt < MT; mt++) {
            f32x4 qa = (f32x4){0.f, 0.f, 0.f, 0.f};
            qa = mfma16(qf[mt][0], bf0, qa);
            qa = mfma16(qf[mt][1], bf1, qa);
#pragma unroll
            for (int reg = 0; reg < 4; reg++)
                qrsw[(mt * 16 + quad * 4 + reg) * 64 + l15 + 16 * nt] = qa[reg];
        }
    }
}

// ------------------------------------------------------------------
// Summary attention, split-K, barrier-free. grid (32, NSPLIT).
// ------------------------------------------------------------------
__global__ __launch_bounds__(256) void sum_attn_split(
    const bf16_t* __restrict__ Qb,   // sum_q [bh][s][d] row-major
    const bf16_t* __restrict__ kfm, const bf16_t* __restrict__ vfm,
    const float*  __restrict__ r0,
    const int*    __restrict__ rel_idx,
    float* __restrict__ po, float* __restrict__ pm, float* __restrict__ pl)
{
    const int bh = blockIdx.x;
    const int split = blockIdx.y;
    const int b = bh >> 4, h = bh & 15;
    const int t = threadIdx.x;
    const int wave = t >> 6, lane = t & 63;
    const int quad = lane >> 4, l15 = lane & 15;

    __shared__ __align__(16) bf16_t Ps[4][16 * 72];
    __shared__ float qrs[4][16 * 64];

    bf16x8 qf[1][2];
    const bf16_t* Qrow = Qb + ((size_t)bh * SLEN + wave * 16 + l15) * HD;
    qf[0][0] = *(const bf16x8*)(Qrow + quad * 8);
    qf[0][1] = *(const bf16x8*)(Qrow + 32 + quad * 8);

    build_qr<1>(r0, h, qf, qrs[wave], quad, l15);

    f32x4 O[1][4];
    float m_q = -1e30f;
    float l_i[1][4];
#pragma unroll
    for (int nt = 0; nt < 4; nt++) O[0][nt] = (f32x4){0.f, 0.f, 0.f, 0.f};
#pragma unroll
    for (int r = 0; r < 4; r++) l_i[0][r] = 0.f;

    const int* relbase = rel_idx + ((size_t)b * KTOT + wave * 16 + quad * 4) * RLEN + 4 * l15;

    const bf16_t* kbase = kfm + (size_t)bh * 131072 + (size_t)(split * 4) * 4096;
    const bf16_t* vbase = vfm + (size_t)bh * 131072 + (size_t)(split * 4) * 4096;

    for (int i = 0; i < 4; i++) {
        const int koff = (split * 4 + i) * 64;
        attn_tile<1>(kbase + (size_t)i * 4096, vbase + (size_t)i * 4096,
                     relbase, koff, true, qrs[wave], Ps[wave], qf,
                     O, m_q, l_i, quad, l15, lane);
    }

    const size_t pslot = (size_t)bh * NSPLIT + split;
#pragma unroll
    for (int nt = 0; nt < 4; nt++)
#pragma unroll
        for (int reg = 0; reg < 4; reg++) {
            int sq = wave * 16 + quad * 4 + reg;
            po[(pslot * SLEN + sq) * HD + l15 + 16 * nt] = O[0][nt][reg];
        }
#pragma unroll
    for (int reg = 0; reg < 4; reg++) {
        int sq = wave * 16 + quad * 4 + reg;
        if (l15 == 0) {
            pm[pslot * SLEN + sq] = m_q;
            pl[pslot * SLEN + sq] = l_i[0][reg];
        }
    }
}

// ------------------------------------------------------------------
// Fused split-reduce + sum_k2/sum_v2 LN projections. One wave per
// (bh, s) row. grid 2048 x 64 threads.
// ------------------------------------------------------------------
__global__ __launch_bounds__(64) void k2v2_fused(
    const float* __restrict__ po, const float* __restrict__ pm,
    const float* __restrict__ pl,
    const float* __restrict__ Wk2, const float* __restrict__ bk2,
    const float* __restrict__ Wv2, const float* __restrict__ bv2,
    const float* __restrict__ gk, const float* __restrict__ bk,
    const float* __restrict__ gv, const float* __restrict__ bv,
    bf16_t* __restrict__ k2fm, bf16_t* __restrict__ v2fm)
{
    int row = blockIdx.x;              // bh*64 + s
    int d = threadIdx.x;
    int bh = row >> 6, s = row & 63;

    // reduce splits for this row
    float M = -1e30f, mm[NSPLIT];
#pragma unroll
    for (int j = 0; j < NSPLIT; j++) {
        mm[j] = pm[((size_t)bh * NSPLIT + j) * SLEN + s];
        M = fmaxf(M, mm[j]);
    }
    float L = 0.f, acc = 0.f;
#pragma unroll
    for (int j = 0; j < NSPLIT; j++) {
        float a = __expf(mm[j] - M);
        L += pl[((size_t)bh * NSPLIT + j) * SLEN + s] * a;
        acc += po[(((size_t)bh * NSPLIT + j) * SLEN + s) * HD + d] * a;
    }
    __shared__ float xs[64];
    xs[d] = acc / L;
    __syncthreads();

#pragma unroll
    for (int which = 0; which < 2; which++) {
        const float* W  = which ? Wv2 : Wk2;
        const float* bi = which ? bv2 : bk2;
        const float* g  = which ? gv : gk;
        const float* bb = which ? bv : bk;
        float a = bi[d];
#pragma unroll
        for (int j = 0; j < 64; j++) a += xs[j] * W[j * HD + d];
        float s1 = a, s2 = a * a;
#pragma unroll
        for (int o = 32; o > 0; o >>= 1) {
            s1 += __shfl_xor(s1, o);
            s2 += __shfl_xor(s2, o);
        }
        float mean = s1 * (1.f / 64.f);
        float var  = s2 * (1.f / 64.f) - mean * mean;
        float y = (a - mean) * rsqrtf(var + 1e-5f) * g[d] + bb[d];
        if (which == 0) {
            size_t off = (size_t)bh * 4096 +
                (size_t)((((s & 3) * 2 + (d >> 5)) * 64
                          + ((d >> 3) & 3) * 16 + (s >> 2)) * 8 + (d & 7));
            k2fm[off] = (bf16_t)y;
        } else {
            size_t off = (size_t)bh * 4096 +
                (size_t)((((d >> 4) * 2 + (s >> 5)) * 64
                          + ((s >> 3) & 3) * 16 + (d & 15)) * 8 + (s & 7));
            v2fm[off] = (bf16_t)y;
        }
    }
}

// ------------------------------------------------------------------
// Main attention, barrier-free MFMA flash. Each wave owns 32 q-rows
// (2 m-frags), streams all 33 key-tiles global->reg. grid 512.
// ------------------------------------------------------------------
__global__ __launch_bounds__(256) void reg_attn_mfma(
    const bf16_t* __restrict__ Qb,    // [bh][r][d] row-major
    const bf16_t* __restrict__ kfm, const bf16_t* __restrict__ vfm,
    const bf16_t* __restrict__ k2fm, const bf16_t* __restrict__ v2fm,
    const float*  __restrict__ r0,
    const int*    __restrict__ rel_idx,
    bf16_t* __restrict__ attn_out)    // [r][b][E] bf16
{
    const int bid = blockIdx.x;       // 512 = 8 XCD x 4 bh x 16 qtiles
    const int bh = (bid & 7) * 4 + ((bid >> 3) & 3);
    const int qt = bid >> 5;          // 0..15
    const int b = bh >> 4, h = bh & 15;
    const int q0 = qt * 128;

    const int t = threadIdx.x;
    const int wave = t >> 6, lane = t & 63;
    const int quad = lane >> 4, l15 = lane & 15;

    __shared__ __align__(16) bf16_t Ps[4][32 * 72];
    __shared__ float qrs[4][32 * 64];

    bf16x8 qf[2][2];
#pragma unroll
    for (int mt = 0; mt < 2; mt++) {
        const bf16_t* Qrow = Qb + ((size_t)bh * RLEN + q0 + wave * 32 + mt * 16 + l15) * HD;
        qf[mt][0] = *(const bf16x8*)(Qrow + quad * 8);
        qf[mt][1] = *(const bf16x8*)(Qrow + 32 + quad * 8);
    }

    build_qr<2>(r0, h, qf, qrs[wave], quad, l15);

    f32x4 O[2][4];
    float m_q = -1e30f;
    float l_i[2][4];
#pragma unroll
    for (int mt = 0; mt < 2; mt++)
#pragma unroll
        for (int nt = 0; nt < 4; nt++) O[mt][nt] = (f32x4){0.f, 0.f, 0.f, 0.f};
#pragma unroll
    for (int mt = 0; mt < 2; mt++)
#pragma unroll
        for (int r = 0; r < 4; r++) l_i[mt][r] = 0.f;

    const int* relbase = rel_idx +
        ((size_t)b * KTOT + SLEN + q0 + wave * 32 + quad * 4) * RLEN + 4 * l15;

    // summary tile (no rel bias), peeled
    attn_tile<2>(k2fm + (size_t)bh * 4096, v2fm + (size_t)bh * 4096,
                 relbase, 0, false, qrs[wave], Ps[wave], qf,
                 O, m_q, l_i, quad, l15, lane);

    const bf16_t* kt = kfm + (size_t)bh * 131072;
    const bf16_t* vt = vfm + (size_t)bh * 131072;
    for (int tile = 0; tile < 32; tile++) {
        attn_tile<2>(kt, vt, relbase, tile * 64, true,
                     qrs[wave], Ps[wave], qf, O, m_q, l_i, quad, l15, lane);
        kt += 4096; vt += 4096;
    }

#pragma unroll
    for (int mt = 0; mt < 2; mt++) {
        float linv[4];
#pragma unroll
        for (int reg = 0; reg < 4; reg++) linv[reg] = 1.0f / l_i[mt][reg];
#pragma unroll
        for (int nt = 0; nt < 4; nt++)
#pragma unroll
            for (int reg = 0; reg < 4; reg++) {
                int q = q0 + wave * 32 + mt * 16 + quad * 4 + reg;
                attn_out[((size_t)q * BSZ + b) * ED + h * HD + l15 + 16 * nt] =
                    (bf16_t)(O[mt][nt][reg] * linv[reg]);
            }
    }
}

// ------------------------------------------------------------------
extern "C" void kernel_launch(void* const* d_in, const int* in_sizes, int n_in,
                              void* d_out, int out_size, void* d_ws, size_t ws_size,
                              hipStream_t stream)
{
    const float* reg_x    = (const float*)d_in[0];
    const int*   sum_ids  = (const int*)d_in[1];
    const int*   rel_idx  = (const int*)d_in[2];
    const float* emb_sum  = (const float*)d_in[5];
    const float* rel_emb0 = (const float*)d_in[6];
    const float* Wq = (const float*)d_in[7];
    const float* bq = (const float*)d_in[8];
    const float* Wk = (const float*)d_in[9];
    const float* bk = (const float*)d_in[10];
    const float* Wv = (const float*)d_in[11];
    const float* bv = (const float*)d_in[12];
    const float* Wr0 = (const float*)d_in[13];
    const float* br0 = (const float*)d_in[14];
    const float* Wk2 = (const float*)d_in[15];
    const float* bk2 = (const float*)d_in[16];
    const float* Wv2 = (const float*)d_in[17];
    const float* bv2 = (const float*)d_in[18];
    const float* Wo  = (const float*)d_in[19];
    const float* bo  = (const float*)d_in[20];
    const float* ln_k_g  = (const float*)d_in[21];
    const float* ln_k_b  = (const float*)d_in[22];
    const float* ln_v_g  = (const float*)d_in[23];
    const float* ln_v_b  = (const float*)d_in[24];
    const float* ln_k2_g = (const float*)d_in[25];
    const float* ln_k2_b = (const float*)d_in[26];
    const float* ln_v2_g = (const float*)d_in[27];
    const float* ln_v2_b = (const float*)d_in[28];

    const size_t QKV = (size_t)BSZ * NH * RLEN * HD;   // 4,194,304
    const size_t SUM = (size_t)BSZ * NH * SLEN * HD;   // 131,072

    float* ws  = (float*)d_ws;
    float* k   = ws;                    // fp32 K; later aliased by aob
    float* v   = k + QKV;               // fp32 V
    float* r0  = v + QKV;

    bf16_t* xb   = (bf16_t*)(r0 + (size_t)NH * NZ * HD);  // dead after QKV -> po
    bf16_t* qb   = xb + QKV;
    bf16_t* kfm  = qb + QKV;
    bf16_t* vfm  = kfm + QKV;
    bf16_t* sqb  = vfm + QKV;
    bf16_t* k2fm = sqb + SUM;
    bf16_t* v2fm = k2fm + SUM;
    bf16_t* wqt  = v2fm + SUM;          // wqt|wkt|wvt contiguous [3072][1024]
    bf16_t* wkt  = wqt + (size_t)ED * ED;
    bf16_t* wvt  = wkt + (size_t)ED * ED;
    bf16_t* wot  = wvt + (size_t)ED * ED;
    bf16_t* wr0t = wot + (size_t)ED * ED;
    bf16_t* re0b = wr0t + (size_t)ED * NZ;
    bf16_t* aob  = (bf16_t*)k;
    float*  po   = (float*)xb;
    float*  pm   = po + (size_t)BSZ * NH * NSPLIT * SLEN * HD;
    float*  pl   = pm + (size_t)BSZ * NH * NSPLIT * SLEN;

    const int M = RLEN * BSZ;   // 4096

    cvt_bf16<<<(int)(QKV / 1024), 256, 0, stream>>>(reg_x, xb, (int)QKV);
    prep_batch<<<1172, 256, 0, stream>>>(Wq, Wk, Wv, Wo, Wr0,
                                         wqt, wkt, wvt, wot, wr0t,
                                         emb_sum, sum_ids, sqb, rel_emb0, re0b);

    gemm_fast<128><<<dim3(3 * ED / 128, M / 128), 256, 0, stream>>>(
        xb, wqt, bq, bk, bv, qb, k, v, M, ED, 3 * ED, 1);

    ln_k_frag<<<(BSZ * NH * RLEN) / 4, 256, 0, stream>>>(k, ln_k_g, ln_k_b, kfm);
    lnv_frag<<<dim3(RLEN / 64, BSZ * NH), 256, 0, stream>>>(v, ln_v_g, ln_v_b, vfm);

    gemm_mfma<<<dim3(ED / 128, 1), 256, 0, stream>>>(re0b, wr0t, br0, r0, NZ, NZ, ED, NZ);

    sum_attn_split<<<dim3(BSZ * NH, NSPLIT), 256, 0, stream>>>(sqb, kfm, vfm, r0, rel_idx, po, pm, pl);

    k2v2_fused<<<BSZ * NH * SLEN, 64, 0, stream>>>(po, pm, pl, Wk2, bk2, Wv2, bv2,
                                                   ln_k2_g, ln_k2_b, ln_v2_g, ln_v2_b,
                                                   k2fm, v2fm);

    reg_attn_mfma<<<512, 256, 0, stream>>>(qb, kfm, vfm, k2fm, v2fm, r0, rel_idx, aob);

    gemm_fast<64><<<dim3(ED / 128, M / 64), 256, 0, stream>>>(
        aob, wot, bo, nullptr, nullptr, nullptr, (float*)d_out, nullptr, M, ED, ED, 0);
}